// Round 12
// baseline (64.524 us; speedup 1.0000x reference)
//
#include <hip/hip_runtime.h>
#include <math.h>

// Problem constants: B=1, S=256, HID=1024, H=16, KV=8, D=64, N_REP=2
#define SCALE 0.125f   // 1/sqrt(64)
#define LOG2E 1.44269504088896340736f

typedef short short8 __attribute__((ext_vector_type(8)));
typedef float floatx4 __attribute__((ext_vector_type(4)));

static __device__ __forceinline__ ushort f2bf(float x) {
  uint32_t b = __float_as_uint(x);
  uint32_t r = (b + 0x7FFFu + ((b >> 16) & 1u)) >> 16;   // RNE
  return (ushort)r;
}
static __device__ __forceinline__ float bf2f(ushort u) {
  return __uint_as_float(((uint32_t)u) << 16);
}

// ---------------------------------------------------------------------------
// MFMA bf16 GEMM 1 + fused RoPE epilogue. Full K=1024. 32x64 tiles -> grid 256
// (R11's 64x64/grid-128 left half the CUs idle). 4 waves: wr=wid&1 (m half),
// wc=wid>>1 (n half, 2 n-tiles each). RoPE pairs (d,d+32) regrouped via LDS.
// grid = 256 (8 m x 32 n), block = 256.
// ---------------------------------------------------------------------------
__global__ __launch_bounds__(256) void gemm_qkv_rope_kernel(
    const float* __restrict__ X, const float* __restrict__ Wq,
    const float* __restrict__ Wk, const float* __restrict__ Wv,
    const float* __restrict__ cosp, const float* __restrict__ sinp,
    float* __restrict__ QKV) {
  __shared__ __align__(16) char lds[12288];   // As 4K | Bs 8K; reused as Ct[32][68]
  char* Asc = lds;
  char* Bsc = lds + 4096;
  const int bx = blockIdx.x;
  const int tile_n = bx & 31, tile_m = bx >> 5;
  const int n0 = tile_n * 64, m0 = tile_m * 32;
  const float* Bp; int ldb, bc0;
  if (n0 < 1024)      { Bp = Wq; ldb = 1024; bc0 = n0; }
  else if (n0 < 1536) { Bp = Wk; ldb = 512;  bc0 = n0 - 1024; }
  else                { Bp = Wv; ldb = 512;  bc0 = n0 - 1536; }
  const int t = threadIdx.x;
  const int arow = t >> 4, acg = t & 15;
  const int bng = t & 15;
  float4 ra[2], rb0[2], rb1[2];
  auto LOAD = [&](int k0) {
    #pragma unroll
    for (int i = 0; i < 2; ++i)
      ra[i] = *reinterpret_cast<const float4*>(X + (size_t)(m0 + arow + 16 * i) * 1024 + k0 + acg * 4);
    #pragma unroll
    for (int i = 0; i < 2; ++i) {
      int k = 2 * ((t >> 4) + 16 * i);
      rb0[i] = *reinterpret_cast<const float4*>(Bp + (size_t)(k0 + k) * ldb + bc0 + bng * 4);
      rb1[i] = *reinterpret_cast<const float4*>(Bp + (size_t)(k0 + k + 1) * ldb + bc0 + bng * 4);
    }
  };
  LOAD(0);
  const int wid = t >> 6, wr = wid & 1, wc = wid >> 1, lane = t & 63;
  const int lr = lane & 15, lk = lane >> 4;
  const int sw = (lr & 7) << 4;
  floatx4 acc[2];
  acc[0] = (floatx4){0.f, 0.f, 0.f, 0.f};
  acc[1] = (floatx4){0.f, 0.f, 0.f, 0.f};
  for (int kt = 0; kt < 16; ++kt) {
    #pragma unroll
    for (int i = 0; i < 2; ++i) {
      int row = arow + 16 * i;
      ushort4 w;
      w.x = f2bf(ra[i].x); w.y = f2bf(ra[i].y); w.z = f2bf(ra[i].z); w.w = f2bf(ra[i].w);
      *reinterpret_cast<ushort4*>(Asc + row * 128 + ((acg * 8) ^ ((row & 7) << 4))) = w;
    }
    #pragma unroll
    for (int i = 0; i < 2; ++i) {
      int k = 2 * ((t >> 4) + 16 * i);
      const float* p0 = (const float*)&rb0[i];
      const float* p1 = (const float*)&rb1[i];
      #pragma unroll
      for (int j = 0; j < 4; ++j) {
        int n = bng * 4 + j;
        uint32_t v = (uint32_t)f2bf(p0[j]) | ((uint32_t)f2bf(p1[j]) << 16);
        *reinterpret_cast<uint32_t*>(Bsc + n * 128 + ((k * 2) ^ ((n & 7) << 4))) = v;
      }
    }
    __syncthreads();
    if (kt + 1 < 16) LOAD(64 * (kt + 1));
    #pragma unroll
    for (int kc = 0; kc < 2; ++kc) {
      short8 af = *reinterpret_cast<const short8*>(
          Asc + (wr * 16 + lr) * 128 + ((kc * 64 + lk * 16) ^ sw));
      #pragma unroll
      for (int nt = 0; nt < 2; ++nt) {
        short8 bf = *reinterpret_cast<const short8*>(
            Bsc + (wc * 32 + nt * 16 + lr) * 128 + ((kc * 64 + lk * 16) ^ sw));
        acc[nt] = __builtin_amdgcn_mfma_f32_16x16x32_bf16(af, bf, acc[nt], 0, 0, 0);
      }
    }
    __syncthreads();
  }
  if (n0 < 1536) {
    // RoPE epilogue: regroup pairs (d, d+32) via LDS round-trip.
    float (*Ct)[68] = (float(*)[68])lds;
    #pragma unroll
    for (int nt = 0; nt < 2; ++nt)
      #pragma unroll
      for (int r = 0; r < 4; ++r)
        Ct[wr * 16 + lk * 4 + r][wc * 32 + nt * 16 + lr] = acc[nt][r];
    __syncthreads();
    #pragma unroll
    for (int i = 0; i < 4; ++i) {
      int pid = t + i * 256;            // 1024 pairs: 32 rows x 32 dp
      int row = pid >> 5, dp = pid & 31;
      float x1 = Ct[row][dp], x2 = Ct[row][dp + 32];
      int s = m0 + row;
      float c1 = cosp[s * 64 + dp],      s1v = sinp[s * 64 + dp];
      float c2 = cosp[s * 64 + dp + 32], s2v = sinp[s * 64 + dp + 32];
      QKV[(size_t)s * 2048 + n0 + dp]      = x1 * c1 - x2 * s1v;
      QKV[(size_t)s * 2048 + n0 + dp + 32] = x2 * c2 + x1 * s2v;
    }
  } else {
    #pragma unroll
    for (int nt = 0; nt < 2; ++nt)
      #pragma unroll
      for (int r = 0; r < 4; ++r) {
        int row = wr * 16 + lk * 4 + r;
        int col = wc * 32 + nt * 16 + lr;
        QKV[(size_t)(m0 + row) * 2048 + n0 + col] = acc[nt][r];
      }
  }
}

// ---------------------------------------------------------------------------
// Fused QK^T + softmax, FP32 QK^T (numerics experiment: bf16-MFMA QK^T is the
// prime suspect for the 0.844 absmax — appeared R6->R7, insensitive to all
// pdiff precision changes). k staged transposed kT[d][t] fp32 (conflict-free
// scalar reads); each lane computes its 4 aw cols directly -> no awsh needed.
// ~69KB LDS -> 2 blocks/CU. grid = 256 (h*16 + j), block = 256.
// ---------------------------------------------------------------------------
__global__ __launch_bounds__(256) void qk_sm_kernel(
    const float* __restrict__ QKV, float* __restrict__ pOut,
    float* __restrict__ awf, float* __restrict__ P2) {
  __shared__ float kT[64][260];    // 66.6KB [d][t]
  __shared__ float qs[16][68];     // 4.25KB [r][d]
  const int h = blockIdx.x >> 4, j = blockIdx.x & 15;
  const int g = h >> 1;
  const int t = threadIdx.x;
  #pragma unroll
  for (int i = 0; i < 16; ++i) {     // stage kT (transpose on write)
    int fi = t + i * 256;
    int tt = fi >> 4, c = (fi & 15) * 4;
    float4 kv = *reinterpret_cast<const float4*>(QKV + (size_t)tt * 2048 + 1024 + g * 64 + c);
    kT[c + 0][tt] = kv.x; kT[c + 1][tt] = kv.y;
    kT[c + 2][tt] = kv.z; kT[c + 3][tt] = kv.w;
  }
  { // stage q strip (16 rows)
    int row = t >> 4, c = (t & 15) * 4;
    float4 qv = *reinterpret_cast<const float4*>(QKV + (size_t)(16 * j + row) * 2048 + h * 64 + c);
    *reinterpret_cast<float4*>(&qs[row][c]) = qv;
  }
  __syncthreads();
  const int w = t >> 6, lane = t & 63;
  for (int rr = 0; rr < 4; ++rr) {
    int row = 4 * w + rr;
    int s = 16 * j + row;
    float a0 = 0.f, a1 = 0.f, a2 = 0.f, a3 = 0.f;
    #pragma unroll 8
    for (int d = 0; d < 64; ++d) {
      float qd = qs[row][d];
      a0 = fmaf(qd, kT[d][lane], a0);
      a1 = fmaf(qd, kT[d][lane + 64], a1);
      a2 = fmaf(qd, kT[d][lane + 128], a2);
      a3 = fmaf(qd, kT[d][lane + 192], a3);
    }
    float v[4] = {a0 * SCALE, a1 * SCALE, a2 * SCALE, a3 * SCALE};
    float m = -3.0e38f;
    #pragma unroll
    for (int i = 0; i < 4; ++i) {
      int tc = lane + 64 * i;
      if (tc > s) v[i] = -3.0e38f;
      m = fmaxf(m, v[i]);
    }
    #pragma unroll
    for (int off = 32; off; off >>= 1) m = fmaxf(m, __shfl_xor(m, off));
    float e[4], sum = 0.f;
    #pragma unroll
    for (int i = 0; i < 4; ++i) {
      int tc = lane + 64 * i;
      e[i] = (tc <= s) ? __expf(v[i] - m) : 0.f;
      sum += e[i];
    }
    #pragma unroll
    for (int off = 32; off; off >>= 1) sum += __shfl_xor(sum, off);
    float inv = 1.f / sum;
    float p2 = 0.f;
    size_t rowbase = ((size_t)h * 256 + s) * 256;
    #pragma unroll
    for (int i = 0; i < 4; ++i) {
      int tc = lane + 64 * i;
      float pv = e[i] * inv;
      pOut[rowbase + tc] = pv;
      p2 = fmaf(pv, pv, p2);
      if (tc <= s) awf[rowbase + tc] = v[i] * LOG2E;
    }
    #pragma unroll
    for (int off = 32; off; off >>= 1) p2 += __shfl_xor(p2, off);
    if (lane == 0) P2[h * 256 + s] = p2;
  }
}

// ---------------------------------------------------------------------------
// Merged p_diff + PV, FP32 k and v in LDS (verified R11). 512 threads.
// wave w: h = 2g+(w&1), jj = 4u+(w>>1); rows jj and 255-jj.
// grid = 256 (8 g * 32 u), block = 512.
// ---------------------------------------------------------------------------
__global__ __launch_bounds__(512) void pdiff_attnv_kernel(
    const float* __restrict__ QKV, const float* __restrict__ awf,
    const float* __restrict__ p, const float* __restrict__ P2,
    float* __restrict__ qkpart, float* __restrict__ attn_out) {
  __shared__ float kls[16384];         // 64KB fp32 [t][d]
  __shared__ float vls[16384];         // 64KB fp32 [t][d]
  __shared__ float rbp[8][2][256];     // 16KB p_t per wave-row
  __shared__ ushort rbw[8][2][256];    // 8KB  bf16(awf_t) per wave-row
  int g = blockIdx.x >> 5;
  int u = blockIdx.x & 31;
  int t = threadIdx.x;
  #pragma unroll
  for (int i = 0; i < 8; ++i) {
    int fi = t + i * 512;              // 4096 float4 slots
    int tt = fi >> 4, c = (fi & 15) * 4;
    *reinterpret_cast<float4*>(&kls[tt * 64 + c]) =
        *reinterpret_cast<const float4*>(QKV + (size_t)tt * 2048 + 1024 + g * 64 + c);
    *reinterpret_cast<float4*>(&vls[tt * 64 + c]) =
        *reinterpret_cast<const float4*>(QKV + (size_t)tt * 2048 + 1536 + g * 64 + c);
  }
  int w = t >> 6, lane = t & 63;
  int h = 2 * g + (w & 1);
  int jj = 4 * u + (w >> 1);
  for (int r = 0; r < 2; ++r) {
    int s = r ? 255 - jj : jj;
    size_t rowbase = ((size_t)h * 256 + s) * 256;
    #pragma unroll
    for (int i = 0; i < 4; ++i) {
      int idx = lane + i * 64;
      rbw[w][r][idx] = f2bf(awf[rowbase + idx]);
      rbp[w][r][idx] = p[rowbase + idx];
    }
  }
  __syncthreads();
  float qk_acc = 0.f;
  for (int r = 0; r < 2; ++r) {
    int s = r ? 255 - jj : jj;
    float cd2 = (SCALE * LOG2E) * QKV[(size_t)s * 2048 + h * 64 + lane];
    float S1 = 0.f, S2 = 0.f, S3 = 0.f, AV = 0.f;
    const float* pr = rbp[w][r];
    const ushort* ar = rbw[w][r];
    for (int tt = 0; tt <= s; ++tt) {
      float kf = kls[tt * 64 + lane];
      float vf = vls[tt * 64 + lane];
      float pv = pr[tt];
      float z2 = fmaf(-cd2, kf, bf2f(ar[tt]));
      float e = exp2f(z2);
      S1 += e;
      S2 = fmaf(e, e, S2);
      S3 = fmaf(e, pv, S3);
      AV = fmaf(pv, vf, AV);
    }
    float inv = 1.f / S1;
    qk_acc += S2 * inv * inv - 2.f * S3 * inv + P2[h * 256 + s];
    attn_out[(size_t)s * 1024 + h * 64 + lane] = AV;
  }
  qkpart[((size_t)h * 128 + jj) * 64 + lane] = qk_acc;
}

// ---------------------------------------------------------------------------
// MFMA bf16 GEMM 2: attn_out(256x1024) @ Wo(1024x1024) -> out partials.
// K-split 8. grid = 512 (8 ks * 64 tiles), block = 256.  (verified R8)
// ---------------------------------------------------------------------------
__global__ __launch_bounds__(256) void gemm_o_kernel(
    const float* __restrict__ A, const float* __restrict__ W,
    float* __restrict__ Cp) {
  __shared__ ushort As[4096];
  __shared__ ushort Bs[4096];
  char* Asc = (char*)As;
  char* Bsc = (char*)Bs;
  const int bx = blockIdx.x;
  const int ks = bx >> 6;            // 0..7
  const int tile = bx & 63;          // 4 m x 16 n
  const int tile_n = tile & 15, tile_m = tile >> 4;
  const int n0 = tile_n * 64, m0 = tile_m * 64;
  const int t = threadIdx.x;
  const int arow = t >> 4, acg = t & 15;
  const int bng = t & 15;
  const int kbeg = ks * 128;
  float4 ra[4], rb0[2], rb1[2];
  auto LOAD = [&](int k0) {
    #pragma unroll
    for (int i = 0; i < 4; ++i)
      ra[i] = *reinterpret_cast<const float4*>(A + (size_t)(m0 + arow + 16 * i) * 1024 + k0 + acg * 4);
    #pragma unroll
    for (int i = 0; i < 2; ++i) {
      int k = 2 * ((t >> 4) + 16 * i);
      rb0[i] = *reinterpret_cast<const float4*>(W + (size_t)(k0 + k) * 1024 + n0 + bng * 4);
      rb1[i] = *reinterpret_cast<const float4*>(W + (size_t)(k0 + k + 1) * 1024 + n0 + bng * 4);
    }
  };
  LOAD(kbeg);
  const int wid = t >> 6, wr = wid >> 1, wc = wid & 1, lane = t & 63;
  const int lr = lane & 15, lk = lane >> 4;
  const int sw = (lr & 7) << 4;
  floatx4 acc[2][2];
  #pragma unroll
  for (int mt = 0; mt < 2; ++mt)
    #pragma unroll
    for (int nt = 0; nt < 2; ++nt)
      acc[mt][nt] = (floatx4){0.f, 0.f, 0.f, 0.f};
  for (int kt = 0; kt < 2; ++kt) {
    #pragma unroll
    for (int i = 0; i < 4; ++i) {
      int row = arow + 16 * i;
      ushort4 w;
      w.x = f2bf(ra[i].x); w.y = f2bf(ra[i].y); w.z = f2bf(ra[i].z); w.w = f2bf(ra[i].w);
      *reinterpret_cast<ushort4*>(Asc + row * 128 + ((acg * 8) ^ ((row & 7) << 4))) = w;
    }
    #pragma unroll
    for (int i = 0; i < 2; ++i) {
      int k = 2 * ((t >> 4) + 16 * i);
      const float* p0 = (const float*)&rb0[i];
      const float* p1 = (const float*)&rb1[i];
      #pragma unroll
      for (int j = 0; j < 4; ++j) {
        int n = bng * 4 + j;
        uint32_t v = (uint32_t)f2bf(p0[j]) | ((uint32_t)f2bf(p1[j]) << 16);
        *reinterpret_cast<uint32_t*>(Bsc + n * 128 + ((k * 2) ^ ((n & 7) << 4))) = v;
      }
    }
    __syncthreads();
    if (kt + 1 < 2) LOAD(kbeg + 64 * (kt + 1));
    #pragma unroll
    for (int kc = 0; kc < 2; ++kc) {
      short8 af[2], bf[2];
      #pragma unroll
      for (int mt = 0; mt < 2; ++mt)
        af[mt] = *reinterpret_cast<const short8*>(
            Asc + (wr * 32 + mt * 16 + lr) * 128 + ((kc * 64 + lk * 16) ^ sw));
      #pragma unroll
      for (int nt = 0; nt < 2; ++nt)
        bf[nt] = *reinterpret_cast<const short8*>(
            Bsc + (wc * 32 + nt * 16 + lr) * 128 + ((kc * 64 + lk * 16) ^ sw));
      #pragma unroll
      for (int mt = 0; mt < 2; ++mt)
        #pragma unroll
        for (int nt = 0; nt < 2; ++nt)
          acc[mt][nt] = __builtin_amdgcn_mfma_f32_16x16x32_bf16(af[mt], bf[nt], acc[mt][nt], 0, 0, 0);
    }
    __syncthreads();
  }
  float* Co = Cp + (size_t)ks * 262144;
  #pragma unroll
  for (int mt = 0; mt < 2; ++mt)
    #pragma unroll
    for (int nt = 0; nt < 2; ++nt)
      #pragma unroll
      for (int r = 0; r < 4; ++r) {
        int row = wr * 32 + mt * 16 + lk * 4 + r;
        int col = wc * 32 + nt * 16 + lr;
        Co[(size_t)(m0 + row) * 1024 + n0 + col] = acc[mt][nt][r];
      }
}

// ---------------------------------------------------------------------------
// Tail: blocks 0..1023 o_reduce (8 partials); 1024..1027 qk_importance;
// 1028..1031 v/o importance. grid = 1032, block = 256.  (verified R8)
// ---------------------------------------------------------------------------
__global__ __launch_bounds__(256) void tail_all_kernel(
    const float* __restrict__ Op, const float* __restrict__ qkpart,
    const float* __restrict__ attn_out, float* __restrict__ out,
    float* __restrict__ qkout, float* __restrict__ vout, float* __restrict__ oout) {
  int b = blockIdx.x, t = threadIdx.x;
  if (b < 1024) {
    int i = b * 256 + t;               // 262144
    float s = 0.f;
    #pragma unroll
    for (int k = 0; k < 8; ++k) s += Op[(size_t)k * 262144 + i];
    out[i] = s;
  } else if (b < 1028) {
    int idx = (b - 1024) * 256 + t;    // 1024 = h*64+d
    int h = idx >> 6, d = idx & 63;
    float sum = 0.f;
    for (int j = 0; j < 128; ++j) sum += qkpart[((size_t)h * 128 + j) * 64 + d];
    qkout[idx] = sum;
  } else {
    int c = (b - 1028) * 256 + t;      // 1024
    float sum = 0.f;
    for (int s = 0; s < 256; ++s) sum += fabsf(attn_out[(size_t)s * 1024 + c]);
    vout[c] = sum;
    oout[c] = sum;
  }
}

// ---------------------------------------------------------------------------
extern "C" void kernel_launch(void* const* d_in, const int* in_sizes, int n_in,
                              void* d_out, int out_size, void* d_ws, size_t ws_size,
                              hipStream_t stream) {
  const float* X    = (const float*)d_in[0];   // hidden_states (1,256,1024)
  const float* cosp = (const float*)d_in[1];   // (1,256,64)
  const float* sinp = (const float*)d_in[2];   // (1,256,64)
  // d_in[3] attention_mask: causal, implemented analytically
  const float* Wq   = (const float*)d_in[4];   // (1024,1024)
  const float* Wk   = (const float*)d_in[5];   // (1024,512)
  const float* Wv   = (const float*)d_in[6];   // (1024,512)
  const float* Wo   = (const float*)d_in[7];   // (1024,1024)

  float* out  = (float*)d_out;                 // 262144
  float* pOut = out + 262144;                  // 1048576
  float* qki  = pOut + 1048576;                // 1024
  float* vi   = qki + 1024;                    // 1024
  float* oi   = vi + 1024;                     // 1024

  float* ws       = (float*)d_ws;
  float* QKV      = ws;                        // 524288 (s-major, 2048 cols: q|k|v)
  float* P2       = ws + 524288;               // 4096
  float* attn_out = ws + 528384;               // 262144
  float* qkpart   = ws + 790528;               // 131072
  float* awf      = ws + 921600;               // 1048576 fp32 (aw*scale*log2e)
  float* scratch  = ws + 1970176;              // 2097152 (O partials x8)

  hipLaunchKernelGGL(gemm_qkv_rope_kernel, dim3(256), dim3(256), 0, stream, X, Wq, Wk, Wv, cosp, sinp, QKV);
  hipLaunchKernelGGL(qk_sm_kernel, dim3(256), dim3(256), 0, stream, QKV, pOut, awf, P2);
  hipLaunchKernelGGL(pdiff_attnv_kernel, dim3(256), dim3(512), 0, stream, QKV, awf, pOut, P2, qkpart, attn_out);
  hipLaunchKernelGGL(gemm_o_kernel, dim3(512), dim3(256), 0, stream, attn_out, Wo, scratch);
  hipLaunchKernelGGL(tail_all_kernel, dim3(1032), dim3(256), 0, stream, scratch, qkpart, attn_out, out, qki, vi, oi);
}

// Round 13
// 58.725 us; speedup vs baseline: 1.0987x; 1.0987x over previous
//
#include <hip/hip_runtime.h>
#include <math.h>

// Problem constants: B=1, S=256, HID=1024, H=16, KV=8, D=64, N_REP=2
#define SCALE 0.125f   // 1/sqrt(64)
#define LOG2E 1.44269504088896340736f

typedef short short8 __attribute__((ext_vector_type(8)));
typedef float floatx4 __attribute__((ext_vector_type(4)));

static __device__ __forceinline__ ushort f2bf(float x) {
  uint32_t b = __float_as_uint(x);
  uint32_t r = (b + 0x7FFFu + ((b >> 16) & 1u)) >> 16;   // RNE
  return (ushort)r;
}
static __device__ __forceinline__ float bf2f(ushort u) {
  return __uint_as_float(((uint32_t)u) << 16);
}

// ---------------------------------------------------------------------------
// MFMA bf16 GEMM 1: X(256x1024) @ [Wq|Wk|Wv](1024x2048) -> QKV partials.
// K-split 4. 64x64 tile, 4 waves (2x2), each wave 32x32 via 2x2 mfma 16x16x32.
// grid = 512 (4 ksplit * 128 tiles), block = 256.  (verified R8, 57.5us config)
// ---------------------------------------------------------------------------
__global__ __launch_bounds__(256) void gemm_qkv_kernel(
    const float* __restrict__ X, const float* __restrict__ Wq,
    const float* __restrict__ Wk, const float* __restrict__ Wv,
    float* __restrict__ Cp) {
  __shared__ ushort As[4096];
  __shared__ ushort Bs[4096];
  char* Asc = (char*)As;
  char* Bsc = (char*)Bs;
  const int bx = blockIdx.x;
  const int ks = bx >> 7;            // 0..3
  const int tile = bx & 127;         // 4 m-tiles x 32 n-tiles
  const int tile_n = tile & 31, tile_m = tile >> 5;
  const int n0 = tile_n * 64, m0 = tile_m * 64;
  const float* Bp; int ldb, bc0;
  if (n0 < 1024)      { Bp = Wq; ldb = 1024; bc0 = n0; }
  else if (n0 < 1536) { Bp = Wk; ldb = 512;  bc0 = n0 - 1024; }
  else                { Bp = Wv; ldb = 512;  bc0 = n0 - 1536; }
  const int t = threadIdx.x;
  const int arow = t >> 4, acg = t & 15;
  const int bng = t & 15;
  const int kbeg = ks * 256;
  float4 ra[4], rb0[2], rb1[2];
  auto LOAD = [&](int k0) {
    #pragma unroll
    for (int i = 0; i < 4; ++i)
      ra[i] = *reinterpret_cast<const float4*>(X + (size_t)(m0 + arow + 16 * i) * 1024 + k0 + acg * 4);
    #pragma unroll
    for (int i = 0; i < 2; ++i) {
      int k = 2 * ((t >> 4) + 16 * i);
      rb0[i] = *reinterpret_cast<const float4*>(Bp + (size_t)(k0 + k) * ldb + bc0 + bng * 4);
      rb1[i] = *reinterpret_cast<const float4*>(Bp + (size_t)(k0 + k + 1) * ldb + bc0 + bng * 4);
    }
  };
  LOAD(kbeg);
  const int wid = t >> 6, wr = wid >> 1, wc = wid & 1, lane = t & 63;
  const int lr = lane & 15, lk = lane >> 4;
  const int sw = (lr & 7) << 4;
  floatx4 acc[2][2];
  #pragma unroll
  for (int mt = 0; mt < 2; ++mt)
    #pragma unroll
    for (int nt = 0; nt < 2; ++nt)
      acc[mt][nt] = (floatx4){0.f, 0.f, 0.f, 0.f};
  for (int kt = 0; kt < 4; ++kt) {
    #pragma unroll
    for (int i = 0; i < 4; ++i) {
      int row = arow + 16 * i;
      ushort4 w;
      w.x = f2bf(ra[i].x); w.y = f2bf(ra[i].y); w.z = f2bf(ra[i].z); w.w = f2bf(ra[i].w);
      *reinterpret_cast<ushort4*>(Asc + row * 128 + ((acg * 8) ^ ((row & 7) << 4))) = w;
    }
    #pragma unroll
    for (int i = 0; i < 2; ++i) {
      int k = 2 * ((t >> 4) + 16 * i);
      const float* p0 = (const float*)&rb0[i];
      const float* p1 = (const float*)&rb1[i];
      #pragma unroll
      for (int j = 0; j < 4; ++j) {
        int n = bng * 4 + j;
        uint32_t v = (uint32_t)f2bf(p0[j]) | ((uint32_t)f2bf(p1[j]) << 16);
        *reinterpret_cast<uint32_t*>(Bsc + n * 128 + ((k * 2) ^ ((n & 7) << 4))) = v;
      }
    }
    __syncthreads();
    if (kt + 1 < 4) LOAD(kbeg + 64 * (kt + 1));
    #pragma unroll
    for (int kc = 0; kc < 2; ++kc) {
      short8 af[2], bf[2];
      #pragma unroll
      for (int mt = 0; mt < 2; ++mt)
        af[mt] = *reinterpret_cast<const short8*>(
            Asc + (wr * 32 + mt * 16 + lr) * 128 + ((kc * 64 + lk * 16) ^ sw));
      #pragma unroll
      for (int nt = 0; nt < 2; ++nt)
        bf[nt] = *reinterpret_cast<const short8*>(
            Bsc + (wc * 32 + nt * 16 + lr) * 128 + ((kc * 64 + lk * 16) ^ sw));
      #pragma unroll
      for (int mt = 0; mt < 2; ++mt)
        #pragma unroll
        for (int nt = 0; nt < 2; ++nt)
          acc[mt][nt] = __builtin_amdgcn_mfma_f32_16x16x32_bf16(af[mt], bf[nt], acc[mt][nt], 0, 0, 0);
    }
    __syncthreads();
  }
  float* Co = Cp + (size_t)ks * 524288;
  #pragma unroll
  for (int mt = 0; mt < 2; ++mt)
    #pragma unroll
    for (int nt = 0; nt < 2; ++nt)
      #pragma unroll
      for (int r = 0; r < 4; ++r) {
        int row = wr * 32 + mt * 16 + lk * 4 + r;
        int col = wc * 32 + nt * 16 + lr;
        Co[(size_t)(m0 + row) * 2048 + n0 + col] = acc[mt][nt][r];
      }
}

// ---------------------------------------------------------------------------
// Reduce the 4 QKV partials + RoPE on q/k heads. grid = 1280, block = 256.
// ---------------------------------------------------------------------------
__global__ __launch_bounds__(256) void rope_reduce_kernel(
    const float* __restrict__ Cp, float* __restrict__ QKV,
    const float* __restrict__ cs, const float* __restrict__ sn) {
  int idx = blockIdx.x * 256 + threadIdx.x;
  const float* P0 = Cp;
  const float* P1 = Cp + 524288;
  const float* P2p = Cp + 1048576;
  const float* P3 = Cp + 1572864;
  if (idx < 196608) {                 // 256 s * 24 heads * 32 pairs
    int dp = idx & 31;
    int head = (idx >> 5) % 24;       // 0..15 q heads, 16..23 k heads
    int s = idx / 768;
    int base = s * 2048 + head * 64;
    int a1 = base + dp, a2 = base + dp + 32;
    float x1 = P0[a1] + P1[a1] + P2p[a1] + P3[a1];
    float x2 = P0[a2] + P1[a2] + P2p[a2] + P3[a2];
    float c1 = cs[s * 64 + dp],      s1v = sn[s * 64 + dp];
    float c2 = cs[s * 64 + dp + 32], s2v = sn[s * 64 + dp + 32];
    QKV[a1] = x1 * c1 - x2 * s1v;   // q' = q*cos + rot_half(q)*sin
    QKV[a2] = x2 * c2 + x1 * s2v;
  } else {
    int i2 = idx - 196608;            // 131072 v elements
    int s = i2 >> 9, c = 1536 + (i2 & 511);
    int a = s * 2048 + c;
    QKV[a] = P0[a] + P1[a] + P2p[a] + P3[a];
  }
}

// ---------------------------------------------------------------------------
// Fused QK^T + softmax (bf16 MFMA — exonerated by R12 null experiment).
// FIX vs R7-R12: awf must carry the SECOND scale factor. Reference:
//   diff = (attn_weights - delta)*scale, attn_weights ALREADY scaled
//   => z = scale^2*(qk) - scale*q_d*k_d. R7 dropped one SCALE (the stable
//   0.844 absmax). awf = v * SCALE * LOG2E now.
// grid = 256 (h*16 + j), block = 256.
// ---------------------------------------------------------------------------
__global__ __launch_bounds__(256) void qk_sm_kernel(
    const float* __restrict__ QKV, float* __restrict__ pOut,
    float* __restrict__ awf, float* __restrict__ P2) {
  __shared__ ushort ksh[16384];      // 32KB swizzled [t][d]
  __shared__ ushort qsh[1024];       // 2KB  swizzled [r][d]
  __shared__ float awsh[16][260];    // padded: conflict-free col reads
  char* kshc = (char*)ksh;
  char* qshc = (char*)qsh;
  const int h = blockIdx.x >> 4, j = blockIdx.x & 15;
  const int g = h >> 1;
  const int t = threadIdx.x;
  #pragma unroll
  for (int i = 0; i < 16; ++i) {     // stage ALL k rows (bf16, XOR swizzle)
    int row = (t >> 4) + 16 * i;
    int c = (t & 15) * 4;
    float4 kv = *reinterpret_cast<const float4*>(QKV + (size_t)row * 2048 + 1024 + g * 64 + c);
    ushort4 w;
    w.x = f2bf(kv.x); w.y = f2bf(kv.y); w.z = f2bf(kv.z); w.w = f2bf(kv.w);
    *reinterpret_cast<ushort4*>(kshc + row * 128 + ((c * 2) ^ ((row & 7) << 4))) = w;
  }
  { // stage q strip (16 rows)
    int row = t >> 4, c = (t & 15) * 4;
    float4 qv = *reinterpret_cast<const float4*>(QKV + (size_t)(16 * j + row) * 2048 + h * 64 + c);
    ushort4 w;
    w.x = f2bf(qv.x); w.y = f2bf(qv.y); w.z = f2bf(qv.z); w.w = f2bf(qv.w);
    *reinterpret_cast<ushort4*>(qshc + row * 128 + ((c * 2) ^ ((row & 7) << 4))) = w;
  }
  __syncthreads();
  const int w = t >> 6, lane = t & 63;
  const int lr = lane & 15, lk = lane >> 4;
  const int sw = (lr & 7) << 4;
  floatx4 acc[4];
  #pragma unroll
  for (int q4 = 0; q4 < 4; ++q4) acc[q4] = (floatx4){0.f, 0.f, 0.f, 0.f};
  #pragma unroll
  for (int q4 = 0; q4 < 4; ++q4) {
    int nt = w + 4 * q4;
    if (nt <= j) {
      #pragma unroll
      for (int kc = 0; kc < 2; ++kc) {
        short8 af = *reinterpret_cast<const short8*>(
            qshc + lr * 128 + ((kc * 64 + lk * 16) ^ sw));
        int tt = nt * 16 + lr;
        short8 bf = *reinterpret_cast<const short8*>(
            kshc + tt * 128 + ((kc * 64 + lk * 16) ^ ((tt & 7) << 4)));
        acc[q4] = __builtin_amdgcn_mfma_f32_16x16x32_bf16(af, bf, acc[q4], 0, 0, 0);
      }
    }
  }
  #pragma unroll
  for (int q4 = 0; q4 < 4; ++q4) {
    int nt = w + 4 * q4;
    if (nt <= j) {
      #pragma unroll
      for (int r = 0; r < 4; ++r)
        awsh[lk * 4 + r][nt * 16 + lr] = acc[q4][r];
    }
  }
  __syncthreads();
  for (int rr = 0; rr < 4; ++rr) {
    int row = 4 * w + rr;
    int s = 16 * j + row;
    float v[4], m = -3.0e38f;
    #pragma unroll
    for (int i = 0; i < 4; ++i) {
      int tc = lane + 64 * i;
      v[i] = (tc <= s) ? awsh[row][tc] * SCALE : -3.0e38f;
      m = fmaxf(m, v[i]);
    }
    #pragma unroll
    for (int off = 32; off; off >>= 1) m = fmaxf(m, __shfl_xor(m, off));
    float e[4], sum = 0.f;
    #pragma unroll
    for (int i = 0; i < 4; ++i) {
      int tc = lane + 64 * i;
      e[i] = (tc <= s) ? __expf(v[i] - m) : 0.f;
      sum += e[i];
    }
    #pragma unroll
    for (int off = 32; off; off >>= 1) sum += __shfl_xor(sum, off);
    float inv = 1.f / sum;
    float p2 = 0.f;
    size_t rowbase = ((size_t)h * 256 + s) * 256;
    #pragma unroll
    for (int i = 0; i < 4; ++i) {
      int tc = lane + 64 * i;
      float pv = e[i] * inv;
      pOut[rowbase + tc] = pv;
      p2 = fmaf(pv, pv, p2);
      if (tc <= s) awf[rowbase + tc] = v[i] * (SCALE * LOG2E);   // <-- THE FIX
    }
    #pragma unroll
    for (int off = 32; off; off >>= 1) p2 += __shfl_xor(p2, off);
    if (lane == 0) P2[h * 256 + s] = p2;
  }
}

// ---------------------------------------------------------------------------
// Merged p_diff + PV, FP32 k and v in LDS. 512 threads (8 waves).
// z2 = awf_t - cd2*k[t,d] with awf = scale^2*qk*LOG2E, cd2 = scale*LOG2E*q_d.
// wave w: h = 2g+(w&1), jj = 4u+(w>>1); rows jj and 255-jj.
// grid = 256 (8 g * 32 u), block = 512.
// ---------------------------------------------------------------------------
__global__ __launch_bounds__(512) void pdiff_attnv_kernel(
    const float* __restrict__ QKV, const float* __restrict__ awf,
    const float* __restrict__ p, const float* __restrict__ P2,
    float* __restrict__ qkpart, float* __restrict__ attn_out) {
  __shared__ float kls[16384];         // 64KB fp32 [t][d]
  __shared__ float vls[16384];         // 64KB fp32 [t][d]
  __shared__ float rbp[8][2][256];     // 16KB p_t per wave-row
  __shared__ ushort rbw[8][2][256];    // 8KB  bf16(awf_t) per wave-row
  int g = blockIdx.x >> 5;
  int u = blockIdx.x & 31;
  int t = threadIdx.x;
  #pragma unroll
  for (int i = 0; i < 8; ++i) {
    int fi = t + i * 512;              // 4096 float4 slots
    int tt = fi >> 4, c = (fi & 15) * 4;
    *reinterpret_cast<float4*>(&kls[tt * 64 + c]) =
        *reinterpret_cast<const float4*>(QKV + (size_t)tt * 2048 + 1024 + g * 64 + c);
    *reinterpret_cast<float4*>(&vls[tt * 64 + c]) =
        *reinterpret_cast<const float4*>(QKV + (size_t)tt * 2048 + 1536 + g * 64 + c);
  }
  int w = t >> 6, lane = t & 63;
  int h = 2 * g + (w & 1);
  int jj = 4 * u + (w >> 1);
  for (int r = 0; r < 2; ++r) {
    int s = r ? 255 - jj : jj;
    size_t rowbase = ((size_t)h * 256 + s) * 256;
    #pragma unroll
    for (int i = 0; i < 4; ++i) {
      int idx = lane + i * 64;
      rbw[w][r][idx] = f2bf(awf[rowbase + idx]);
      rbp[w][r][idx] = p[rowbase + idx];
    }
  }
  __syncthreads();
  float qk_acc = 0.f;
  for (int r = 0; r < 2; ++r) {
    int s = r ? 255 - jj : jj;
    float cd2 = (SCALE * LOG2E) * QKV[(size_t)s * 2048 + h * 64 + lane];
    float S1 = 0.f, S2 = 0.f, S3 = 0.f, AV = 0.f;
    const float* pr = rbp[w][r];
    const ushort* ar = rbw[w][r];
    for (int tt = 0; tt <= s; ++tt) {
      float kf = kls[tt * 64 + lane];
      float vf = vls[tt * 64 + lane];
      float pv = pr[tt];
      float z2 = fmaf(-cd2, kf, bf2f(ar[tt]));
      float e = exp2f(z2);
      S1 += e;
      S2 = fmaf(e, e, S2);
      S3 = fmaf(e, pv, S3);
      AV = fmaf(pv, vf, AV);
    }
    float inv = 1.f / S1;
    qk_acc += S2 * inv * inv - 2.f * S3 * inv + P2[h * 256 + s];
    attn_out[(size_t)s * 1024 + h * 64 + lane] = AV;
  }
  qkpart[((size_t)h * 128 + jj) * 64 + lane] = qk_acc;
}

// ---------------------------------------------------------------------------
// MFMA bf16 GEMM 2: attn_out(256x1024) @ Wo(1024x1024) -> out partials.
// K-split 8. grid = 512 (8 ks * 64 tiles), block = 256.  (verified R8)
// ---------------------------------------------------------------------------
__global__ __launch_bounds__(256) void gemm_o_kernel(
    const float* __restrict__ A, const float* __restrict__ W,
    float* __restrict__ Cp) {
  __shared__ ushort As[4096];
  __shared__ ushort Bs[4096];
  char* Asc = (char*)As;
  char* Bsc = (char*)Bs;
  const int bx = blockIdx.x;
  const int ks = bx >> 6;            // 0..7
  const int tile = bx & 63;          // 4 m x 16 n
  const int tile_n = tile & 15, tile_m = tile >> 4;
  const int n0 = tile_n * 64, m0 = tile_m * 64;
  const int t = threadIdx.x;
  const int arow = t >> 4, acg = t & 15;
  const int bng = t & 15;
  const int kbeg = ks * 128;
  float4 ra[4], rb0[2], rb1[2];
  auto LOAD = [&](int k0) {
    #pragma unroll
    for (int i = 0; i < 4; ++i)
      ra[i] = *reinterpret_cast<const float4*>(A + (size_t)(m0 + arow + 16 * i) * 1024 + k0 + acg * 4);
    #pragma unroll
    for (int i = 0; i < 2; ++i) {
      int k = 2 * ((t >> 4) + 16 * i);
      rb0[i] = *reinterpret_cast<const float4*>(W + (size_t)(k0 + k) * 1024 + n0 + bng * 4);
      rb1[i] = *reinterpret_cast<const float4*>(W + (size_t)(k0 + k + 1) * 1024 + n0 + bng * 4);
    }
  };
  LOAD(kbeg);
  const int wid = t >> 6, wr = wid >> 1, wc = wid & 1, lane = t & 63;
  const int lr = lane & 15, lk = lane >> 4;
  const int sw = (lr & 7) << 4;
  floatx4 acc[2][2];
  #pragma unroll
  for (int mt = 0; mt < 2; ++mt)
    #pragma unroll
    for (int nt = 0; nt < 2; ++nt)
      acc[mt][nt] = (floatx4){0.f, 0.f, 0.f, 0.f};
  for (int kt = 0; kt < 2; ++kt) {
    #pragma unroll
    for (int i = 0; i < 4; ++i) {
      int row = arow + 16 * i;
      ushort4 w;
      w.x = f2bf(ra[i].x); w.y = f2bf(ra[i].y); w.z = f2bf(ra[i].z); w.w = f2bf(ra[i].w);
      *reinterpret_cast<ushort4*>(Asc + row * 128 + ((acg * 8) ^ ((row & 7) << 4))) = w;
    }
    #pragma unroll
    for (int i = 0; i < 2; ++i) {
      int k = 2 * ((t >> 4) + 16 * i);
      const float* p0 = (const float*)&rb0[i];
      const float* p1 = (const float*)&rb1[i];
      #pragma unroll
      for (int j = 0; j < 4; ++j) {
        int n = bng * 4 + j;
        uint32_t v = (uint32_t)f2bf(p0[j]) | ((uint32_t)f2bf(p1[j]) << 16);
        *reinterpret_cast<uint32_t*>(Bsc + n * 128 + ((k * 2) ^ ((n & 7) << 4))) = v;
      }
    }
    __syncthreads();
    if (kt + 1 < 2) LOAD(kbeg + 64 * (kt + 1));
    #pragma unroll
    for (int kc = 0; kc < 2; ++kc) {
      short8 af[2], bf[2];
      #pragma unroll
      for (int mt = 0; mt < 2; ++mt)
        af[mt] = *reinterpret_cast<const short8*>(
            Asc + (wr * 32 + mt * 16 + lr) * 128 + ((kc * 64 + lk * 16) ^ sw));
      #pragma unroll
      for (int nt = 0; nt < 2; ++nt)
        bf[nt] = *reinterpret_cast<const short8*>(
            Bsc + (wc * 32 + nt * 16 + lr) * 128 + ((kc * 64 + lk * 16) ^ sw));
      #pragma unroll
      for (int mt = 0; mt < 2; ++mt)
        #pragma unroll
        for (int nt = 0; nt < 2; ++nt)
          acc[mt][nt] = __builtin_amdgcn_mfma_f32_16x16x32_bf16(af[mt], bf[nt], acc[mt][nt], 0, 0, 0);
    }
    __syncthreads();
  }
  float* Co = Cp + (size_t)ks * 262144;
  #pragma unroll
  for (int mt = 0; mt < 2; ++mt)
    #pragma unroll
    for (int nt = 0; nt < 2; ++nt)
      #pragma unroll
      for (int r = 0; r < 4; ++r) {
        int row = wr * 32 + mt * 16 + lk * 4 + r;
        int col = wc * 32 + nt * 16 + lr;
        Co[(size_t)(m0 + row) * 1024 + n0 + col] = acc[mt][nt][r];
      }
}

// ---------------------------------------------------------------------------
// Tail: blocks 0..1023 o_reduce (8 partials); 1024..1027 qk_importance;
// 1028..1031 v/o importance. grid = 1032, block = 256.  (verified R8)
// ---------------------------------------------------------------------------
__global__ __launch_bounds__(256) void tail_all_kernel(
    const float* __restrict__ Op, const float* __restrict__ qkpart,
    const float* __restrict__ attn_out, float* __restrict__ out,
    float* __restrict__ qkout, float* __restrict__ vout, float* __restrict__ oout) {
  int b = blockIdx.x, t = threadIdx.x;
  if (b < 1024) {
    int i = b * 256 + t;               // 262144
    float s = 0.f;
    #pragma unroll
    for (int k = 0; k < 8; ++k) s += Op[(size_t)k * 262144 + i];
    out[i] = s;
  } else if (b < 1028) {
    int idx = (b - 1024) * 256 + t;    // 1024 = h*64+d
    int h = idx >> 6, d = idx & 63;
    float sum = 0.f;
    for (int j = 0; j < 128; ++j) sum += qkpart[((size_t)h * 128 + j) * 64 + d];
    qkout[idx] = sum;
  } else {
    int c = (b - 1028) * 256 + t;      // 1024
    float sum = 0.f;
    for (int s = 0; s < 256; ++s) sum += fabsf(attn_out[(size_t)s * 1024 + c]);
    vout[c] = sum;
    oout[c] = sum;
  }
}

// ---------------------------------------------------------------------------
extern "C" void kernel_launch(void* const* d_in, const int* in_sizes, int n_in,
                              void* d_out, int out_size, void* d_ws, size_t ws_size,
                              hipStream_t stream) {
  const float* X    = (const float*)d_in[0];   // hidden_states (1,256,1024)
  const float* cosp = (const float*)d_in[1];   // (1,256,64)
  const float* sinp = (const float*)d_in[2];   // (1,256,64)
  // d_in[3] attention_mask: causal, implemented analytically
  const float* Wq   = (const float*)d_in[4];   // (1024,1024)
  const float* Wk   = (const float*)d_in[5];   // (1024,512)
  const float* Wv   = (const float*)d_in[6];   // (1024,512)
  const float* Wo   = (const float*)d_in[7];   // (1024,1024)

  float* out  = (float*)d_out;                 // 262144
  float* pOut = out + 262144;                  // 1048576
  float* qki  = pOut + 1048576;                // 1024
  float* vi   = qki + 1024;                    // 1024
  float* oi   = vi + 1024;                     // 1024

  float* ws       = (float*)d_ws;
  float* QKV      = ws;                        // 524288 (s-major, 2048 cols: q|k|v)
  float* P2       = ws + 524288;               // 4096
  float* attn_out = ws + 528384;               // 262144
  float* qkpart   = ws + 790528;               // 131072
  float* awf      = ws + 921600;               // 1048576 fp32 (aw*scale^2*log2e)
  float* scratch  = ws + 1970176;              // 2097152 (QKV partials x4; O partials x8)

  hipLaunchKernelGGL(gemm_qkv_kernel, dim3(512), dim3(256), 0, stream, X, Wq, Wk, Wv, scratch);
  hipLaunchKernelGGL(rope_reduce_kernel, dim3(1280), dim3(256), 0, stream, scratch, QKV, cosp, sinp);
  hipLaunchKernelGGL(qk_sm_kernel, dim3(256), dim3(256), 0, stream, QKV, pOut, awf, P2);
  hipLaunchKernelGGL(pdiff_attnv_kernel, dim3(256), dim3(512), 0, stream, QKV, awf, pOut, P2, qkpart, attn_out);
  hipLaunchKernelGGL(gemm_o_kernel, dim3(512), dim3(256), 0, stream, attn_out, Wo, scratch);
  hipLaunchKernelGGL(tail_all_kernel, dim3(1032), dim3(256), 0, stream, scratch, qkpart, attn_out, out, qki, vi, oi);
}

// Round 14
// 58.466 us; speedup vs baseline: 1.1036x; 1.0044x over previous
//
#include <hip/hip_runtime.h>
#include <math.h>

// Problem constants: B=1, S=256, HID=1024, H=16, KV=8, D=64, N_REP=2
#define SCALE 0.125f   // 1/sqrt(64)
#define LOG2E 1.44269504088896340736f

typedef short short8 __attribute__((ext_vector_type(8)));
typedef float floatx4 __attribute__((ext_vector_type(4)));

static __device__ __forceinline__ ushort f2bf(float x) {
  uint32_t b = __float_as_uint(x);
  uint32_t r = (b + 0x7FFFu + ((b >> 16) & 1u)) >> 16;   // RNE
  return (ushort)r;
}
static __device__ __forceinline__ float bf2f(ushort u) {
  return __uint_as_float(((uint32_t)u) << 16);
}

// ---------------------------------------------------------------------------
// MFMA bf16 GEMM 1: X(256x1024) @ [Wq|Wk|Wv](1024x2048) -> QKV partials.
// K-split 4. 64x64 tile, 4 waves (2x2), each wave 32x32 via 2x2 mfma 16x16x32.
// grid = 512 (4 ksplit * 128 tiles), block = 256.  (verified R8/R13)
// ---------------------------------------------------------------------------
__global__ __launch_bounds__(256) void gemm_qkv_kernel(
    const float* __restrict__ X, const float* __restrict__ Wq,
    const float* __restrict__ Wk, const float* __restrict__ Wv,
    float* __restrict__ Cp) {
  __shared__ ushort As[4096];
  __shared__ ushort Bs[4096];
  char* Asc = (char*)As;
  char* Bsc = (char*)Bs;
  const int bx = blockIdx.x;
  const int ks = bx >> 7;            // 0..3
  const int tile = bx & 127;         // 4 m-tiles x 32 n-tiles
  const int tile_n = tile & 31, tile_m = tile >> 5;
  const int n0 = tile_n * 64, m0 = tile_m * 64;
  const float* Bp; int ldb, bc0;
  if (n0 < 1024)      { Bp = Wq; ldb = 1024; bc0 = n0; }
  else if (n0 < 1536) { Bp = Wk; ldb = 512;  bc0 = n0 - 1024; }
  else                { Bp = Wv; ldb = 512;  bc0 = n0 - 1536; }
  const int t = threadIdx.x;
  const int arow = t >> 4, acg = t & 15;
  const int bng = t & 15;
  const int kbeg = ks * 256;
  float4 ra[4], rb0[2], rb1[2];
  auto LOAD = [&](int k0) {
    #pragma unroll
    for (int i = 0; i < 4; ++i)
      ra[i] = *reinterpret_cast<const float4*>(X + (size_t)(m0 + arow + 16 * i) * 1024 + k0 + acg * 4);
    #pragma unroll
    for (int i = 0; i < 2; ++i) {
      int k = 2 * ((t >> 4) + 16 * i);
      rb0[i] = *reinterpret_cast<const float4*>(Bp + (size_t)(k0 + k) * ldb + bc0 + bng * 4);
      rb1[i] = *reinterpret_cast<const float4*>(Bp + (size_t)(k0 + k + 1) * ldb + bc0 + bng * 4);
    }
  };
  LOAD(kbeg);
  const int wid = t >> 6, wr = wid >> 1, wc = wid & 1, lane = t & 63;
  const int lr = lane & 15, lk = lane >> 4;
  const int sw = (lr & 7) << 4;
  floatx4 acc[2][2];
  #pragma unroll
  for (int mt = 0; mt < 2; ++mt)
    #pragma unroll
    for (int nt = 0; nt < 2; ++nt)
      acc[mt][nt] = (floatx4){0.f, 0.f, 0.f, 0.f};
  for (int kt = 0; kt < 4; ++kt) {
    #pragma unroll
    for (int i = 0; i < 4; ++i) {
      int row = arow + 16 * i;
      ushort4 w;
      w.x = f2bf(ra[i].x); w.y = f2bf(ra[i].y); w.z = f2bf(ra[i].z); w.w = f2bf(ra[i].w);
      *reinterpret_cast<ushort4*>(Asc + row * 128 + ((acg * 8) ^ ((row & 7) << 4))) = w;
    }
    #pragma unroll
    for (int i = 0; i < 2; ++i) {
      int k = 2 * ((t >> 4) + 16 * i);
      const float* p0 = (const float*)&rb0[i];
      const float* p1 = (const float*)&rb1[i];
      #pragma unroll
      for (int j = 0; j < 4; ++j) {
        int n = bng * 4 + j;
        uint32_t v = (uint32_t)f2bf(p0[j]) | ((uint32_t)f2bf(p1[j]) << 16);
        *reinterpret_cast<uint32_t*>(Bsc + n * 128 + ((k * 2) ^ ((n & 7) << 4))) = v;
      }
    }
    __syncthreads();
    if (kt + 1 < 4) LOAD(kbeg + 64 * (kt + 1));
    #pragma unroll
    for (int kc = 0; kc < 2; ++kc) {
      short8 af[2], bf[2];
      #pragma unroll
      for (int mt = 0; mt < 2; ++mt)
        af[mt] = *reinterpret_cast<const short8*>(
            Asc + (wr * 32 + mt * 16 + lr) * 128 + ((kc * 64 + lk * 16) ^ sw));
      #pragma unroll
      for (int nt = 0; nt < 2; ++nt)
        bf[nt] = *reinterpret_cast<const short8*>(
            Bsc + (wc * 32 + nt * 16 + lr) * 128 + ((kc * 64 + lk * 16) ^ sw));
      #pragma unroll
      for (int mt = 0; mt < 2; ++mt)
        #pragma unroll
        for (int nt = 0; nt < 2; ++nt)
          acc[mt][nt] = __builtin_amdgcn_mfma_f32_16x16x32_bf16(af[mt], bf[nt], acc[mt][nt], 0, 0, 0);
    }
    __syncthreads();
  }
  float* Co = Cp + (size_t)ks * 524288;
  #pragma unroll
  for (int mt = 0; mt < 2; ++mt)
    #pragma unroll
    for (int nt = 0; nt < 2; ++nt)
      #pragma unroll
      for (int r = 0; r < 4; ++r) {
        int row = wr * 32 + mt * 16 + lk * 4 + r;
        int col = wc * 32 + nt * 16 + lr;
        Co[(size_t)(m0 + row) * 2048 + n0 + col] = acc[mt][nt][r];
      }
}

// ---------------------------------------------------------------------------
// Reduce the 4 QKV partials + RoPE on q/k heads. grid = 1280, block = 256.
// ---------------------------------------------------------------------------
__global__ __launch_bounds__(256) void rope_reduce_kernel(
    const float* __restrict__ Cp, float* __restrict__ QKV,
    const float* __restrict__ cs, const float* __restrict__ sn) {
  int idx = blockIdx.x * 256 + threadIdx.x;
  const float* P0 = Cp;
  const float* P1 = Cp + 524288;
  const float* P2p = Cp + 1048576;
  const float* P3 = Cp + 1572864;
  if (idx < 196608) {                 // 256 s * 24 heads * 32 pairs
    int dp = idx & 31;
    int head = (idx >> 5) % 24;       // 0..15 q heads, 16..23 k heads
    int s = idx / 768;
    int base = s * 2048 + head * 64;
    int a1 = base + dp, a2 = base + dp + 32;
    float x1 = P0[a1] + P1[a1] + P2p[a1] + P3[a1];
    float x2 = P0[a2] + P1[a2] + P2p[a2] + P3[a2];
    float c1 = cs[s * 64 + dp],      s1v = sn[s * 64 + dp];
    float c2 = cs[s * 64 + dp + 32], s2v = sn[s * 64 + dp + 32];
    QKV[a1] = x1 * c1 - x2 * s1v;   // q' = q*cos + rot_half(q)*sin
    QKV[a2] = x2 * c2 + x1 * s2v;
  } else {
    int i2 = idx - 196608;            // 131072 v elements
    int s = i2 >> 9, c = 1536 + (i2 & 511);
    int a = s * 2048 + c;
    QKV[a] = P0[a] + P1[a] + P2p[a] + P3[a];
  }
}

// ---------------------------------------------------------------------------
// Fused QK^T + softmax (verified R13: awf carries BOTH scale factors).
// Writes p (fp32), P2 = sum p^2, awf = fp32(aw*scale^2*log2e).
// grid = 256 (h*16 + j), block = 256.
// ---------------------------------------------------------------------------
__global__ __launch_bounds__(256) void qk_sm_kernel(
    const float* __restrict__ QKV, float* __restrict__ pOut,
    float* __restrict__ awf, float* __restrict__ P2) {
  __shared__ ushort ksh[16384];      // 32KB swizzled [t][d]
  __shared__ ushort qsh[1024];       // 2KB  swizzled [r][d]
  __shared__ float awsh[16][260];    // padded: conflict-free col reads
  char* kshc = (char*)ksh;
  char* qshc = (char*)qsh;
  const int h = blockIdx.x >> 4, j = blockIdx.x & 15;
  const int g = h >> 1;
  const int t = threadIdx.x;
  #pragma unroll
  for (int i = 0; i < 16; ++i) {     // stage ALL k rows (bf16, XOR swizzle)
    int row = (t >> 4) + 16 * i;
    int c = (t & 15) * 4;
    float4 kv = *reinterpret_cast<const float4*>(QKV + (size_t)row * 2048 + 1024 + g * 64 + c);
    ushort4 w;
    w.x = f2bf(kv.x); w.y = f2bf(kv.y); w.z = f2bf(kv.z); w.w = f2bf(kv.w);
    *reinterpret_cast<ushort4*>(kshc + row * 128 + ((c * 2) ^ ((row & 7) << 4))) = w;
  }
  { // stage q strip (16 rows)
    int row = t >> 4, c = (t & 15) * 4;
    float4 qv = *reinterpret_cast<const float4*>(QKV + (size_t)(16 * j + row) * 2048 + h * 64 + c);
    ushort4 w;
    w.x = f2bf(qv.x); w.y = f2bf(qv.y); w.z = f2bf(qv.z); w.w = f2bf(qv.w);
    *reinterpret_cast<ushort4*>(qshc + row * 128 + ((c * 2) ^ ((row & 7) << 4))) = w;
  }
  __syncthreads();
  const int w = t >> 6, lane = t & 63;
  const int lr = lane & 15, lk = lane >> 4;
  const int sw = (lr & 7) << 4;
  floatx4 acc[4];
  #pragma unroll
  for (int q4 = 0; q4 < 4; ++q4) acc[q4] = (floatx4){0.f, 0.f, 0.f, 0.f};
  #pragma unroll
  for (int q4 = 0; q4 < 4; ++q4) {
    int nt = w + 4 * q4;
    if (nt <= j) {
      #pragma unroll
      for (int kc = 0; kc < 2; ++kc) {
        short8 af = *reinterpret_cast<const short8*>(
            qshc + lr * 128 + ((kc * 64 + lk * 16) ^ sw));
        int tt = nt * 16 + lr;
        short8 bf = *reinterpret_cast<const short8*>(
            kshc + tt * 128 + ((kc * 64 + lk * 16) ^ ((tt & 7) << 4)));
        acc[q4] = __builtin_amdgcn_mfma_f32_16x16x32_bf16(af, bf, acc[q4], 0, 0, 0);
      }
    }
  }
  #pragma unroll
  for (int q4 = 0; q4 < 4; ++q4) {
    int nt = w + 4 * q4;
    if (nt <= j) {
      #pragma unroll
      for (int r = 0; r < 4; ++r)
        awsh[lk * 4 + r][nt * 16 + lr] = acc[q4][r];
    }
  }
  __syncthreads();
  for (int rr = 0; rr < 4; ++rr) {
    int row = 4 * w + rr;
    int s = 16 * j + row;
    float v[4], m = -3.0e38f;
    #pragma unroll
    for (int i = 0; i < 4; ++i) {
      int tc = lane + 64 * i;
      v[i] = (tc <= s) ? awsh[row][tc] * SCALE : -3.0e38f;
      m = fmaxf(m, v[i]);
    }
    #pragma unroll
    for (int off = 32; off; off >>= 1) m = fmaxf(m, __shfl_xor(m, off));
    float e[4], sum = 0.f;
    #pragma unroll
    for (int i = 0; i < 4; ++i) {
      int tc = lane + 64 * i;
      e[i] = (tc <= s) ? __expf(v[i] - m) : 0.f;
      sum += e[i];
    }
    #pragma unroll
    for (int off = 32; off; off >>= 1) sum += __shfl_xor(sum, off);
    float inv = 1.f / sum;
    float p2 = 0.f;
    size_t rowbase = ((size_t)h * 256 + s) * 256;
    #pragma unroll
    for (int i = 0; i < 4; ++i) {
      int tc = lane + 64 * i;
      float pv = e[i] * inv;
      pOut[rowbase + tc] = pv;
      p2 = fmaf(pv, pv, p2);
      if (tc <= s) awf[rowbase + tc] = v[i] * (SCALE * LOG2E);   // both scales (R13 fix)
    }
    #pragma unroll
    for (int off = 32; off; off >>= 1) p2 += __shfl_xor(p2, off);
    if (lane == 0) P2[h * 256 + s] = p2;
  }
}

// ---------------------------------------------------------------------------
// Merged p_diff + PV — LDS-instruction diet: 4 -> 2 LDS reads/iter.
// kvp[t][d] = k bf16 | v bf16 packed u32 (lane=d -> 2-way bank alias, free).
// rbc[w][r][t] = aw bf16 | p bf16 packed u32 (uniform addr -> broadcast).
// aw bf16 verified R13; p bf16 internal only (p output stays fp32);
// v bf16 fallback pre-registered: if absmax > 0.6 revert v to fp32.
// grid = 256 (8 g * 32 u), block = 512.
// ---------------------------------------------------------------------------
__global__ __launch_bounds__(512) void pdiff_attnv_kernel(
    const float* __restrict__ QKV, const float* __restrict__ awf,
    const float* __restrict__ p, const float* __restrict__ P2,
    float* __restrict__ qkpart, float* __restrict__ attn_out) {
  __shared__ uint32_t kvp[16384];      // 64KB [t][d]: k bf16 lo | v bf16 hi
  __shared__ uint32_t rbc[8][2][256];  // 16KB: aw bf16 lo | p bf16 hi
  int g = blockIdx.x >> 5;
  int u = blockIdx.x & 31;
  int t = threadIdx.x;
  #pragma unroll
  for (int i = 0; i < 8; ++i) {
    int fi = t + i * 512;              // 4096 float4 slots
    int tt = fi >> 4, c = (fi & 15) * 4;
    float4 kv = *reinterpret_cast<const float4*>(QKV + (size_t)tt * 2048 + 1024 + g * 64 + c);
    float4 vv = *reinterpret_cast<const float4*>(QKV + (size_t)tt * 2048 + 1536 + g * 64 + c);
    uint4 pk;
    pk.x = (uint32_t)f2bf(kv.x) | ((uint32_t)f2bf(vv.x) << 16);
    pk.y = (uint32_t)f2bf(kv.y) | ((uint32_t)f2bf(vv.y) << 16);
    pk.z = (uint32_t)f2bf(kv.z) | ((uint32_t)f2bf(vv.z) << 16);
    pk.w = (uint32_t)f2bf(kv.w) | ((uint32_t)f2bf(vv.w) << 16);
    *reinterpret_cast<uint4*>(&kvp[tt * 64 + c]) = pk;
  }
  int w = t >> 6, lane = t & 63;
  int h = 2 * g + (w & 1);
  int jj = 4 * u + (w >> 1);
  for (int r = 0; r < 2; ++r) {
    int s = r ? 255 - jj : jj;
    size_t rowbase = ((size_t)h * 256 + s) * 256;
    #pragma unroll
    for (int i = 0; i < 4; ++i) {
      int idx = lane + i * 64;
      rbc[w][r][idx] = (uint32_t)f2bf(awf[rowbase + idx])
                     | ((uint32_t)f2bf(p[rowbase + idx]) << 16);
    }
  }
  __syncthreads();
  float qk_acc = 0.f;
  for (int r = 0; r < 2; ++r) {
    int s = r ? 255 - jj : jj;
    float cd2 = (SCALE * LOG2E) * QKV[(size_t)s * 2048 + h * 64 + lane];
    float S1 = 0.f, S2 = 0.f, S3 = 0.f, AV = 0.f;
    const uint32_t* rbr = rbc[w][r];
    for (int tt = 0; tt <= s; ++tt) {
      uint32_t kv = kvp[tt * 64 + lane];
      uint32_t ap = rbr[tt];
      float kf = __uint_as_float(kv << 16);
      float vf = __uint_as_float(kv & 0xFFFF0000u);
      float aw = __uint_as_float(ap << 16);
      float pv = __uint_as_float(ap & 0xFFFF0000u);
      float z2 = fmaf(-cd2, kf, aw);
      float e = exp2f(z2);
      S1 += e;
      S2 = fmaf(e, e, S2);
      S3 = fmaf(e, pv, S3);
      AV = fmaf(pv, vf, AV);
    }
    float inv = 1.f / S1;
    qk_acc += S2 * inv * inv - 2.f * S3 * inv + P2[h * 256 + s];
    attn_out[(size_t)s * 1024 + h * 64 + lane] = AV;
  }
  qkpart[((size_t)h * 128 + jj) * 64 + lane] = qk_acc;
}

// ---------------------------------------------------------------------------
// MFMA bf16 GEMM 2: attn_out(256x1024) @ Wo(1024x1024) -> out partials.
// K-split 8. grid = 512 (8 ks * 64 tiles), block = 256.  (verified R8/R13)
// ---------------------------------------------------------------------------
__global__ __launch_bounds__(256) void gemm_o_kernel(
    const float* __restrict__ A, const float* __restrict__ W,
    float* __restrict__ Cp) {
  __shared__ ushort As[4096];
  __shared__ ushort Bs[4096];
  char* Asc = (char*)As;
  char* Bsc = (char*)Bs;
  const int bx = blockIdx.x;
  const int ks = bx >> 6;            // 0..7
  const int tile = bx & 63;          // 4 m x 16 n
  const int tile_n = tile & 15, tile_m = tile >> 4;
  const int n0 = tile_n * 64, m0 = tile_m * 64;
  const int t = threadIdx.x;
  const int arow = t >> 4, acg = t & 15;
  const int bng = t & 15;
  const int kbeg = ks * 128;
  float4 ra[4], rb0[2], rb1[2];
  auto LOAD = [&](int k0) {
    #pragma unroll
    for (int i = 0; i < 4; ++i)
      ra[i] = *reinterpret_cast<const float4*>(A + (size_t)(m0 + arow + 16 * i) * 1024 + k0 + acg * 4);
    #pragma unroll
    for (int i = 0; i < 2; ++i) {
      int k = 2 * ((t >> 4) + 16 * i);
      rb0[i] = *reinterpret_cast<const float4*>(W + (size_t)(k0 + k) * 1024 + n0 + bng * 4);
      rb1[i] = *reinterpret_cast<const float4*>(W + (size_t)(k0 + k + 1) * 1024 + n0 + bng * 4);
    }
  };
  LOAD(kbeg);
  const int wid = t >> 6, wr = wid >> 1, wc = wid & 1, lane = t & 63;
  const int lr = lane & 15, lk = lane >> 4;
  const int sw = (lr & 7) << 4;
  floatx4 acc[2][2];
  #pragma unroll
  for (int mt = 0; mt < 2; ++mt)
    #pragma unroll
    for (int nt = 0; nt < 2; ++nt)
      acc[mt][nt] = (floatx4){0.f, 0.f, 0.f, 0.f};
  for (int kt = 0; kt < 2; ++kt) {
    #pragma unroll
    for (int i = 0; i < 4; ++i) {
      int row = arow + 16 * i;
      ushort4 w;
      w.x = f2bf(ra[i].x); w.y = f2bf(ra[i].y); w.z = f2bf(ra[i].z); w.w = f2bf(ra[i].w);
      *reinterpret_cast<ushort4*>(Asc + row * 128 + ((acg * 8) ^ ((row & 7) << 4))) = w;
    }
    #pragma unroll
    for (int i = 0; i < 2; ++i) {
      int k = 2 * ((t >> 4) + 16 * i);
      const float* p0 = (const float*)&rb0[i];
      const float* p1 = (const float*)&rb1[i];
      #pragma unroll
      for (int j = 0; j < 4; ++j) {
        int n = bng * 4 + j;
        uint32_t v = (uint32_t)f2bf(p0[j]) | ((uint32_t)f2bf(p1[j]) << 16);
        *reinterpret_cast<uint32_t*>(Bsc + n * 128 + ((k * 2) ^ ((n & 7) << 4))) = v;
      }
    }
    __syncthreads();
    if (kt + 1 < 2) LOAD(kbeg + 64 * (kt + 1));
    #pragma unroll
    for (int kc = 0; kc < 2; ++kc) {
      short8 af[2], bf[2];
      #pragma unroll
      for (int mt = 0; mt < 2; ++mt)
        af[mt] = *reinterpret_cast<const short8*>(
            Asc + (wr * 32 + mt * 16 + lr) * 128 + ((kc * 64 + lk * 16) ^ sw));
      #pragma unroll
      for (int nt = 0; nt < 2; ++nt)
        bf[nt] = *reinterpret_cast<const short8*>(
            Bsc + (wc * 32 + nt * 16 + lr) * 128 + ((kc * 64 + lk * 16) ^ sw));
      #pragma unroll
      for (int mt = 0; mt < 2; ++mt)
        #pragma unroll
        for (int nt = 0; nt < 2; ++nt)
          acc[mt][nt] = __builtin_amdgcn_mfma_f32_16x16x32_bf16(af[mt], bf[nt], acc[mt][nt], 0, 0, 0);
    }
    __syncthreads();
  }
  float* Co = Cp + (size_t)ks * 262144;
  #pragma unroll
  for (int mt = 0; mt < 2; ++mt)
    #pragma unroll
    for (int nt = 0; nt < 2; ++nt)
      #pragma unroll
      for (int r = 0; r < 4; ++r) {
        int row = wr * 32 + mt * 16 + lk * 4 + r;
        int col = wc * 32 + nt * 16 + lr;
        Co[(size_t)(m0 + row) * 1024 + n0 + col] = acc[mt][nt][r];
      }
}

// ---------------------------------------------------------------------------
// Tail: blocks 0..1023 o_reduce (8 partials); 1024..1027 qk_importance;
// 1028..1031 v/o importance. grid = 1032, block = 256.  (verified R8/R13)
// ---------------------------------------------------------------------------
__global__ __launch_bounds__(256) void tail_all_kernel(
    const float* __restrict__ Op, const float* __restrict__ qkpart,
    const float* __restrict__ attn_out, float* __restrict__ out,
    float* __restrict__ qkout, float* __restrict__ vout, float* __restrict__ oout) {
  int b = blockIdx.x, t = threadIdx.x;
  if (b < 1024) {
    int i = b * 256 + t;               // 262144
    float s = 0.f;
    #pragma unroll
    for (int k = 0; k < 8; ++k) s += Op[(size_t)k * 262144 + i];
    out[i] = s;
  } else if (b < 1028) {
    int idx = (b - 1024) * 256 + t;    // 1024 = h*64+d
    int h = idx >> 6, d = idx & 63;
    float sum = 0.f;
    for (int j = 0; j < 128; ++j) sum += qkpart[((size_t)h * 128 + j) * 64 + d];
    qkout[idx] = sum;
  } else {
    int c = (b - 1028) * 256 + t;      // 1024
    float sum = 0.f;
    for (int s = 0; s < 256; ++s) sum += fabsf(attn_out[(size_t)s * 1024 + c]);
    vout[c] = sum;
    oout[c] = sum;
  }
}

// ---------------------------------------------------------------------------
extern "C" void kernel_launch(void* const* d_in, const int* in_sizes, int n_in,
                              void* d_out, int out_size, void* d_ws, size_t ws_size,
                              hipStream_t stream) {
  const float* X    = (const float*)d_in[0];   // hidden_states (1,256,1024)
  const float* cosp = (const float*)d_in[1];   // (1,256,64)
  const float* sinp = (const float*)d_in[2];   // (1,256,64)
  // d_in[3] attention_mask: causal, implemented analytically
  const float* Wq   = (const float*)d_in[4];   // (1024,1024)
  const float* Wk   = (const float*)d_in[5];   // (1024,512)
  const float* Wv   = (const float*)d_in[6];   // (1024,512)
  const float* Wo   = (const float*)d_in[7];   // (1024,1024)

  float* out  = (float*)d_out;                 // 262144
  float* pOut = out + 262144;                  // 1048576
  float* qki  = pOut + 1048576;                // 1024
  float* vi   = qki + 1024;                    // 1024
  float* oi   = vi + 1024;                     // 1024

  float* ws       = (float*)d_ws;
  float* QKV      = ws;                        // 524288 (s-major, 2048 cols: q|k|v)
  float* P2       = ws + 524288;               // 4096
  float* attn_out = ws + 528384;               // 262144
  float* qkpart   = ws + 790528;               // 131072
  float* awf      = ws + 921600;               // 1048576 fp32 (aw*scale^2*log2e)
  float* scratch  = ws + 1970176;              // 2097152 (QKV partials x4; O partials x8)

  hipLaunchKernelGGL(gemm_qkv_kernel, dim3(512), dim3(256), 0, stream, X, Wq, Wk, Wv, scratch);
  hipLaunchKernelGGL(rope_reduce_kernel, dim3(1280), dim3(256), 0, stream, scratch, QKV, cosp, sinp);
  hipLaunchKernelGGL(qk_sm_kernel, dim3(256), dim3(256), 0, stream, QKV, pOut, awf, P2);
  hipLaunchKernelGGL(pdiff_attnv_kernel, dim3(256), dim3(512), 0, stream, QKV, awf, pOut, P2, qkpart, attn_out);
  hipLaunchKernelGGL(gemm_o_kernel, dim3(512), dim3(256), 0, stream, attn_out, Wo, scratch);
  hipLaunchKernelGGL(tail_all_kernel, dim3(1032), dim3(256), 0, stream, scratch, qkpart, attn_out, out, qki, vi, oi);
}

// Round 15
// 57.027 us; speedup vs baseline: 1.1315x; 1.0252x over previous
//
#include <hip/hip_runtime.h>
#include <math.h>

// Problem constants: B=1, S=256, HID=1024, H=16, KV=8, D=64, N_REP=2
#define SCALE 0.125f   // 1/sqrt(64)
#define LOG2E 1.44269504088896340736f

typedef short short8 __attribute__((ext_vector_type(8)));
typedef float floatx4 __attribute__((ext_vector_type(4)));

static __device__ __forceinline__ ushort f2bf(float x) {
  uint32_t b = __float_as_uint(x);
  uint32_t r = (b + 0x7FFFu + ((b >> 16) & 1u)) >> 16;   // RNE
  return (ushort)r;
}

// ---------------------------------------------------------------------------
// MFMA bf16 GEMM 1: X(256x1024) @ [Wq|Wk|Wv](1024x2048) -> QKV partials.
// K-split 4. grid = 512 (4 ksplit * 128 tiles), block = 256. (verified R8/R13)
// ---------------------------------------------------------------------------
__global__ __launch_bounds__(256) void gemm_qkv_kernel(
    const float* __restrict__ X, const float* __restrict__ Wq,
    const float* __restrict__ Wk, const float* __restrict__ Wv,
    float* __restrict__ Cp) {
  __shared__ ushort As[4096];
  __shared__ ushort Bs[4096];
  char* Asc = (char*)As;
  char* Bsc = (char*)Bs;
  const int bx = blockIdx.x;
  const int ks = bx >> 7;            // 0..3
  const int tile = bx & 127;         // 4 m-tiles x 32 n-tiles
  const int tile_n = tile & 31, tile_m = tile >> 5;
  const int n0 = tile_n * 64, m0 = tile_m * 64;
  const float* Bp; int ldb, bc0;
  if (n0 < 1024)      { Bp = Wq; ldb = 1024; bc0 = n0; }
  else if (n0 < 1536) { Bp = Wk; ldb = 512;  bc0 = n0 - 1024; }
  else                { Bp = Wv; ldb = 512;  bc0 = n0 - 1536; }
  const int t = threadIdx.x;
  const int arow = t >> 4, acg = t & 15;
  const int bng = t & 15;
  const int kbeg = ks * 256;
  float4 ra[4], rb0[2], rb1[2];
  auto LOAD = [&](int k0) {
    #pragma unroll
    for (int i = 0; i < 4; ++i)
      ra[i] = *reinterpret_cast<const float4*>(X + (size_t)(m0 + arow + 16 * i) * 1024 + k0 + acg * 4);
    #pragma unroll
    for (int i = 0; i < 2; ++i) {
      int k = 2 * ((t >> 4) + 16 * i);
      rb0[i] = *reinterpret_cast<const float4*>(Bp + (size_t)(k0 + k) * ldb + bc0 + bng * 4);
      rb1[i] = *reinterpret_cast<const float4*>(Bp + (size_t)(k0 + k + 1) * ldb + bc0 + bng * 4);
    }
  };
  LOAD(kbeg);
  const int wid = t >> 6, wr = wid >> 1, wc = wid & 1, lane = t & 63;
  const int lr = lane & 15, lk = lane >> 4;
  const int sw = (lr & 7) << 4;
  floatx4 acc[2][2];
  #pragma unroll
  for (int mt = 0; mt < 2; ++mt)
    #pragma unroll
    for (int nt = 0; nt < 2; ++nt)
      acc[mt][nt] = (floatx4){0.f, 0.f, 0.f, 0.f};
  for (int kt = 0; kt < 4; ++kt) {
    #pragma unroll
    for (int i = 0; i < 4; ++i) {
      int row = arow + 16 * i;
      ushort4 w;
      w.x = f2bf(ra[i].x); w.y = f2bf(ra[i].y); w.z = f2bf(ra[i].z); w.w = f2bf(ra[i].w);
      *reinterpret_cast<ushort4*>(Asc + row * 128 + ((acg * 8) ^ ((row & 7) << 4))) = w;
    }
    #pragma unroll
    for (int i = 0; i < 2; ++i) {
      int k = 2 * ((t >> 4) + 16 * i);
      const float* p0 = (const float*)&rb0[i];
      const float* p1 = (const float*)&rb1[i];
      #pragma unroll
      for (int j = 0; j < 4; ++j) {
        int n = bng * 4 + j;
        uint32_t v = (uint32_t)f2bf(p0[j]) | ((uint32_t)f2bf(p1[j]) << 16);
        *reinterpret_cast<uint32_t*>(Bsc + n * 128 + ((k * 2) ^ ((n & 7) << 4))) = v;
      }
    }
    __syncthreads();
    if (kt + 1 < 4) LOAD(kbeg + 64 * (kt + 1));
    #pragma unroll
    for (int kc = 0; kc < 2; ++kc) {
      short8 af[2], bf[2];
      #pragma unroll
      for (int mt = 0; mt < 2; ++mt)
        af[mt] = *reinterpret_cast<const short8*>(
            Asc + (wr * 32 + mt * 16 + lr) * 128 + ((kc * 64 + lk * 16) ^ sw));
      #pragma unroll
      for (int nt = 0; nt < 2; ++nt)
        bf[nt] = *reinterpret_cast<const short8*>(
            Bsc + (wc * 32 + nt * 16 + lr) * 128 + ((kc * 64 + lk * 16) ^ sw));
      #pragma unroll
      for (int mt = 0; mt < 2; ++mt)
        #pragma unroll
        for (int nt = 0; nt < 2; ++nt)
          acc[mt][nt] = __builtin_amdgcn_mfma_f32_16x16x32_bf16(af[mt], bf[nt], acc[mt][nt], 0, 0, 0);
    }
    __syncthreads();
  }
  float* Co = Cp + (size_t)ks * 524288;
  #pragma unroll
  for (int mt = 0; mt < 2; ++mt)
    #pragma unroll
    for (int nt = 0; nt < 2; ++nt)
      #pragma unroll
      for (int r = 0; r < 4; ++r) {
        int row = wr * 32 + mt * 16 + lk * 4 + r;
        int col = wc * 32 + nt * 16 + lr;
        Co[(size_t)(m0 + row) * 2048 + n0 + col] = acc[mt][nt][r];
      }
}

// ---------------------------------------------------------------------------
// Reduce the 4 QKV partials + RoPE on q/k heads. grid = 1280, block = 256.
// ---------------------------------------------------------------------------
__global__ __launch_bounds__(256) void rope_reduce_kernel(
    const float* __restrict__ Cp, float* __restrict__ QKV,
    const float* __restrict__ cs, const float* __restrict__ sn) {
  int idx = blockIdx.x * 256 + threadIdx.x;
  const float* P0 = Cp;
  const float* P1 = Cp + 524288;
  const float* P2p = Cp + 1048576;
  const float* P3 = Cp + 1572864;
  if (idx < 196608) {                 // 256 s * 24 heads * 32 pairs
    int dp = idx & 31;
    int head = (idx >> 5) % 24;       // 0..15 q heads, 16..23 k heads
    int s = idx / 768;
    int base = s * 2048 + head * 64;
    int a1 = base + dp, a2 = base + dp + 32;
    float x1 = P0[a1] + P1[a1] + P2p[a1] + P3[a1];
    float x2 = P0[a2] + P1[a2] + P2p[a2] + P3[a2];
    float c1 = cs[s * 64 + dp],      s1v = sn[s * 64 + dp];
    float c2 = cs[s * 64 + dp + 32], s2v = sn[s * 64 + dp + 32];
    QKV[a1] = x1 * c1 - x2 * s1v;   // q' = q*cos + rot_half(q)*sin
    QKV[a2] = x2 * c2 + x1 * s2v;
  } else {
    int i2 = idx - 196608;            // 131072 v elements
    int s = i2 >> 9, c = 1536 + (i2 & 511);
    int a = s * 2048 + c;
    QKV[a] = P0[a] + P1[a] + P2p[a] + P3[a];
  }
}

// ---------------------------------------------------------------------------
// QK^T MFMA only (softmax moved into pdiff). Writes awf = scale^2*log2e*qk
// fp32 directly from acc registers, causal region only.
// grid = 256 (h*16 + j), block = 256.
// ---------------------------------------------------------------------------
__global__ __launch_bounds__(256) void qk_aw_kernel(
    const float* __restrict__ QKV, float* __restrict__ awf) {
  __shared__ ushort ksh[16384];      // 32KB swizzled [t][d]
  __shared__ ushort qsh[1024];       // 2KB  swizzled [r][d]
  char* kshc = (char*)ksh;
  char* qshc = (char*)qsh;
  const int h = blockIdx.x >> 4, j = blockIdx.x & 15;
  const int g = h >> 1;
  const int t = threadIdx.x;
  #pragma unroll
  for (int i = 0; i < 16; ++i) {     // stage ALL k rows (bf16, XOR swizzle)
    int row = (t >> 4) + 16 * i;
    int c = (t & 15) * 4;
    float4 kv = *reinterpret_cast<const float4*>(QKV + (size_t)row * 2048 + 1024 + g * 64 + c);
    ushort4 w;
    w.x = f2bf(kv.x); w.y = f2bf(kv.y); w.z = f2bf(kv.z); w.w = f2bf(kv.w);
    *reinterpret_cast<ushort4*>(kshc + row * 128 + ((c * 2) ^ ((row & 7) << 4))) = w;
  }
  { // stage q strip (16 rows)
    int row = t >> 4, c = (t & 15) * 4;
    float4 qv = *reinterpret_cast<const float4*>(QKV + (size_t)(16 * j + row) * 2048 + h * 64 + c);
    ushort4 w;
    w.x = f2bf(qv.x); w.y = f2bf(qv.y); w.z = f2bf(qv.z); w.w = f2bf(qv.w);
    *reinterpret_cast<ushort4*>(qshc + row * 128 + ((c * 2) ^ ((row & 7) << 4))) = w;
  }
  __syncthreads();
  const int w = t >> 6, lane = t & 63;
  const int lr = lane & 15, lk = lane >> 4;
  const int sw = (lr & 7) << 4;
  floatx4 acc[4];
  #pragma unroll
  for (int q4 = 0; q4 < 4; ++q4) acc[q4] = (floatx4){0.f, 0.f, 0.f, 0.f};
  #pragma unroll
  for (int q4 = 0; q4 < 4; ++q4) {
    int nt = w + 4 * q4;
    if (nt <= j) {
      #pragma unroll
      for (int kc = 0; kc < 2; ++kc) {
        short8 af = *reinterpret_cast<const short8*>(
            qshc + lr * 128 + ((kc * 64 + lk * 16) ^ sw));
        int tt = nt * 16 + lr;
        short8 bf = *reinterpret_cast<const short8*>(
            kshc + tt * 128 + ((kc * 64 + lk * 16) ^ ((tt & 7) << 4)));
        acc[q4] = __builtin_amdgcn_mfma_f32_16x16x32_bf16(af, bf, acc[q4], 0, 0, 0);
      }
    }
  }
  const float AWS = SCALE * SCALE * LOG2E;
  #pragma unroll
  for (int q4 = 0; q4 < 4; ++q4) {
    int nt = w + 4 * q4;
    if (nt <= j) {
      #pragma unroll
      for (int r = 0; r < 4; ++r) {
        int s = 16 * j + lk * 4 + r;
        int tc = nt * 16 + lr;
        if (tc <= s) awf[((size_t)h * 256 + s) * 256 + tc] = acc[q4][r] * AWS;
      }
    }
  }
}

// ---------------------------------------------------------------------------
// Mega p_diff: softmax(p) + p_diff sums + PV + p output + |AV| partials.
// Max-free softmax: ep_t = exp2(8*awf_t) (args bounded ~7); p = ep/Sp;
//   P2 = sum p^2 = P2'/Sp^2; S3 = sum e*p = S3'/Sp; AV = AV'/Sp.
// qk row-part = S2/S1^2 - 2*S3'/(S1*Sp) + P2'/Sp^2.
// kvp: k|v bf16 packed (1 ds_read); rbc: awf fp32 broadcast (1 ds_read).
// grid = 256 (8 g * 32 u), block = 512; LDS 80KB -> 2 blocks/CU.
// ---------------------------------------------------------------------------
__global__ __launch_bounds__(512) void pdiff_kernel(
    const float* __restrict__ QKV, const float* __restrict__ awf,
    float* __restrict__ pOut, float* __restrict__ qkpart,
    float* __restrict__ vpart, float* __restrict__ attn_out) {
  __shared__ uint32_t kvp[16384];      // 64KB [t][d]: k bf16 lo | v bf16 hi
  __shared__ float rbc[8][2][256];     // 16KB awf fp32 per wave-row
  int g = blockIdx.x >> 5;
  int u = blockIdx.x & 31;
  int t = threadIdx.x;
  #pragma unroll
  for (int i = 0; i < 8; ++i) {
    int fi = t + i * 512;              // 4096 float4 slots
    int tt = fi >> 4, c = (fi & 15) * 4;
    float4 kv = *reinterpret_cast<const float4*>(QKV + (size_t)tt * 2048 + 1024 + g * 64 + c);
    float4 vv = *reinterpret_cast<const float4*>(QKV + (size_t)tt * 2048 + 1536 + g * 64 + c);
    uint4 pk;
    pk.x = (uint32_t)f2bf(kv.x) | ((uint32_t)f2bf(vv.x) << 16);
    pk.y = (uint32_t)f2bf(kv.y) | ((uint32_t)f2bf(vv.y) << 16);
    pk.z = (uint32_t)f2bf(kv.z) | ((uint32_t)f2bf(vv.z) << 16);
    pk.w = (uint32_t)f2bf(kv.w) | ((uint32_t)f2bf(vv.w) << 16);
    *reinterpret_cast<uint4*>(&kvp[tt * 64 + c]) = pk;
  }
  int w = t >> 6, lane = t & 63;
  int h = 2 * g + (w & 1);
  int jj = 4 * u + (w >> 1);
  for (int r = 0; r < 2; ++r) {
    int s = r ? 255 - jj : jj;
    size_t rowbase = ((size_t)h * 256 + s) * 256;
    #pragma unroll
    for (int i = 0; i < 4; ++i) {
      int idx = lane + i * 64;
      rbc[w][r][idx] = awf[rowbase + idx];
    }
  }
  __syncthreads();
  float qk_acc = 0.f, v_acc = 0.f;
  for (int r = 0; r < 2; ++r) {
    int s = r ? 255 - jj : jj;
    size_t rowbase = ((size_t)h * 256 + s) * 256;
    float cd2 = (SCALE * LOG2E) * QKV[(size_t)s * 2048 + h * 64 + lane];
    float S1 = 0.f, S2 = 0.f, S3p = 0.f, Sp = 0.f, P2p = 0.f, AVp = 0.f;
    const float* rbr = rbc[w][r];
    for (int tt = 0; tt <= s; ++tt) {
      uint32_t kv = kvp[tt * 64 + lane];
      float kf = __uint_as_float(kv << 16);
      float vf = __uint_as_float(kv & 0xFFFF0000u);
      float aw = rbr[tt];
      float e  = exp2f(fmaf(-cd2, kf, aw));
      float ep = exp2f(aw * 8.0f);
      S1 += e;
      S2  = fmaf(e, e, S2);
      S3p = fmaf(e, ep, S3p);
      Sp += ep;
      P2p = fmaf(ep, ep, P2p);
      AVp = fmaf(ep, vf, AVp);
    }
    float invS1 = 1.f / S1;
    float invSp = 1.f / Sp;
    qk_acc += S2 * invS1 * invS1 - 2.f * S3p * invS1 * invSp + P2p * invSp * invSp;
    float av = AVp * invSp;
    attn_out[(size_t)s * 1024 + h * 64 + lane] = av;
    v_acc += fabsf(av);
    #pragma unroll
    for (int i = 0; i < 4; ++i) {
      int tc = lane + i * 64;
      pOut[rowbase + tc] = (tc <= s) ? exp2f(rbr[tc] * 8.0f) * invSp : 0.f;
    }
  }
  qkpart[((size_t)h * 128 + jj) * 64 + lane] = qk_acc;
  vpart [((size_t)h * 128 + jj) * 64 + lane] = v_acc;
}

// ---------------------------------------------------------------------------
// GEMM 2 + tail in ONE dispatch. Blocks 0..255: 32x32-tile FULL-K bf16 MFMA,
// direct write to out (no partials, no reduce). Blocks 256..263: qk/v/o
// importance reductions (inputs from prior dispatch -> no sync needed).
// grid = 264, block = 256.
// ---------------------------------------------------------------------------
__global__ __launch_bounds__(256) void gemm_o_tail_kernel(
    const float* __restrict__ A, const float* __restrict__ W,
    const float* __restrict__ qkpart, const float* __restrict__ vpart,
    float* __restrict__ out, float* __restrict__ qkout,
    float* __restrict__ vout, float* __restrict__ oout) {
  __shared__ ushort As[2048];   // 32 rows x 64 k bf16, XOR swizzle
  __shared__ ushort Bs[2048];   // 32 n    x 64 k
  char* Asc = (char*)As;
  char* Bsc = (char*)Bs;
  const int b = blockIdx.x, t = threadIdx.x;
  if (b < 256) {
    const int tm = b >> 5, tn = b & 31;       // 8 m x 32 n tiles
    const int m0 = tm * 32, n0 = tn * 32;
    const int arow = t >> 3, aslot = t & 7;   // A: 32 rows x 16 slots
    const int kp = t >> 3, ng = t & 7;        // B: 32 kpairs x 8 ngroups
    float4 ra[2], rb0, rb1;
    auto LOAD = [&](int k0) {
      #pragma unroll
      for (int i = 0; i < 2; ++i)
        ra[i] = *reinterpret_cast<const float4*>(A + (size_t)(m0 + arow) * 1024 + k0 + (aslot + 8 * i) * 4);
      rb0 = *reinterpret_cast<const float4*>(W + (size_t)(k0 + 2 * kp) * 1024 + n0 + ng * 4);
      rb1 = *reinterpret_cast<const float4*>(W + (size_t)(k0 + 2 * kp + 1) * 1024 + n0 + ng * 4);
    };
    LOAD(0);
    const int wid = t >> 6, qm = wid >> 1, qn = wid & 1, lane = t & 63;
    const int lr = lane & 15, lk = lane >> 4;
    const int sw = (lr & 7) << 4;
    floatx4 acc = (floatx4){0.f, 0.f, 0.f, 0.f};
    for (int kt = 0; kt < 16; ++kt) {
      #pragma unroll
      for (int i = 0; i < 2; ++i) {
        int c = (aslot + 8 * i) * 4;
        ushort4 wv;
        wv.x = f2bf(ra[i].x); wv.y = f2bf(ra[i].y); wv.z = f2bf(ra[i].z); wv.w = f2bf(ra[i].w);
        *reinterpret_cast<ushort4*>(Asc + arow * 128 + ((c * 2) ^ ((arow & 7) << 4))) = wv;
      }
      {
        const float* p0 = (const float*)&rb0;
        const float* p1 = (const float*)&rb1;
        #pragma unroll
        for (int j = 0; j < 4; ++j) {
          int n = ng * 4 + j;
          uint32_t v = (uint32_t)f2bf(p0[j]) | ((uint32_t)f2bf(p1[j]) << 16);
          *reinterpret_cast<uint32_t*>(Bsc + n * 128 + ((kp * 4) ^ ((n & 7) << 4))) = v;
        }
      }
      __syncthreads();
      if (kt + 1 < 16) LOAD(64 * (kt + 1));
      #pragma unroll
      for (int kc = 0; kc < 2; ++kc) {
        short8 af = *reinterpret_cast<const short8*>(
            Asc + (qm * 16 + lr) * 128 + ((kc * 64 + lk * 16) ^ sw));
        short8 bf = *reinterpret_cast<const short8*>(
            Bsc + (qn * 16 + lr) * 128 + ((kc * 64 + lk * 16) ^ sw));
        acc = __builtin_amdgcn_mfma_f32_16x16x32_bf16(af, bf, acc, 0, 0, 0);
      }
      __syncthreads();
    }
    #pragma unroll
    for (int r = 0; r < 4; ++r) {
      int row = m0 + qm * 16 + lk * 4 + r;
      int col = n0 + qn * 16 + lr;
      out[(size_t)row * 1024 + col] = acc[r];
    }
  } else {
    int idx = (b - 256) * 256 + t;            // 0..2047
    if (idx < 1024) {
      int h = idx >> 6, d = idx & 63;
      float sum = 0.f;
      for (int j = 0; j < 128; ++j) sum += qkpart[((size_t)h * 128 + j) * 64 + d];
      qkout[idx] = sum;
    } else {
      int c = idx - 1024;
      int h = c >> 6, d = c & 63;
      float sum = 0.f;
      for (int j = 0; j < 128; ++j) sum += vpart[((size_t)h * 128 + j) * 64 + d];
      vout[c] = sum;
      oout[c] = sum;
    }
  }
}

// ---------------------------------------------------------------------------
extern "C" void kernel_launch(void* const* d_in, const int* in_sizes, int n_in,
                              void* d_out, int out_size, void* d_ws, size_t ws_size,
                              hipStream_t stream) {
  const float* X    = (const float*)d_in[0];   // hidden_states (1,256,1024)
  const float* cosp = (const float*)d_in[1];   // (1,256,64)
  const float* sinp = (const float*)d_in[2];   // (1,256,64)
  // d_in[3] attention_mask: causal, implemented analytically
  const float* Wq   = (const float*)d_in[4];   // (1024,1024)
  const float* Wk   = (const float*)d_in[5];   // (1024,512)
  const float* Wv   = (const float*)d_in[6];   // (1024,512)
  const float* Wo   = (const float*)d_in[7];   // (1024,1024)

  float* out  = (float*)d_out;                 // 262144
  float* pOut = out + 262144;                  // 1048576
  float* qki  = pOut + 1048576;                // 1024
  float* vi   = qki + 1024;                    // 1024
  float* oi   = vi + 1024;                     // 1024

  float* ws       = (float*)d_ws;
  float* QKV      = ws;                        // 524288 (s-major, 2048 cols: q|k|v)
  float* attn_out = ws + 524288;               // 262144
  float* qkpart   = ws + 786432;               // 131072
  float* vpart    = ws + 917504;               // 131072
  float* awf      = ws + 1048576;              // 1048576 fp32 (scale^2*log2e*qk)
  float* scratch  = ws + 2097152;              // 2097152 (QKV partials x4)

  hipLaunchKernelGGL(gemm_qkv_kernel, dim3(512), dim3(256), 0, stream, X, Wq, Wk, Wv, scratch);
  hipLaunchKernelGGL(rope_reduce_kernel, dim3(1280), dim3(256), 0, stream, scratch, QKV, cosp, sinp);
  hipLaunchKernelGGL(qk_aw_kernel, dim3(256), dim3(256), 0, stream, QKV, awf);
  hipLaunchKernelGGL(pdiff_kernel, dim3(256), dim3(512), 0, stream, QKV, awf, pOut, qkpart, vpart, attn_out);
  hipLaunchKernelGGL(gemm_o_tail_kernel, dim3(264), dim3(256), 0, stream, attn_out, Wo, qkpart, vpart, out, qki, vi, oi);
}

// Round 18
// 56.052 us; speedup vs baseline: 1.1511x; 1.0174x over previous
//
#include <hip/hip_runtime.h>
#include <math.h>

// Problem constants: B=1, S=256, HID=1024, H=16, KV=8, D=64, N_REP=2
#define SCALE 0.125f   // 1/sqrt(64)
#define LOG2E 1.44269504088896340736f

typedef short short8 __attribute__((ext_vector_type(8)));
typedef float floatx4 __attribute__((ext_vector_type(4)));

static __device__ __forceinline__ ushort f2bf(float x) {
  uint32_t b = __float_as_uint(x);
  uint32_t r = (b + 0x7FFFu + ((b >> 16) & 1u)) >> 16;   // RNE
  return (ushort)r;
}
static __device__ __forceinline__ float bf2f(ushort u) {
  return __uint_as_float(((uint32_t)u) << 16);
}

// ---------------------------------------------------------------------------
// MFMA bf16 GEMM 1: X(256x1024) @ [Wq|Wk|Wv](1024x2048) -> QKV partials.
// K-split 4. grid = 512 (4 ksplit * 128 tiles), block = 256. (verified R8/R13)
// ---------------------------------------------------------------------------
__global__ __launch_bounds__(256) void gemm_qkv_kernel(
    const float* __restrict__ X, const float* __restrict__ Wq,
    const float* __restrict__ Wk, const float* __restrict__ Wv,
    float* __restrict__ Cp) {
  __shared__ ushort As[4096];
  __shared__ ushort Bs[4096];
  char* Asc = (char*)As;
  char* Bsc = (char*)Bs;
  const int bx = blockIdx.x;
  const int ks = bx >> 7;            // 0..3
  const int tile = bx & 127;         // 4 m-tiles x 32 n-tiles
  const int tile_n = tile & 31, tile_m = tile >> 5;
  const int n0 = tile_n * 64, m0 = tile_m * 64;
  const float* Bp; int ldb, bc0;
  if (n0 < 1024)      { Bp = Wq; ldb = 1024; bc0 = n0; }
  else if (n0 < 1536) { Bp = Wk; ldb = 512;  bc0 = n0 - 1024; }
  else                { Bp = Wv; ldb = 512;  bc0 = n0 - 1536; }
  const int t = threadIdx.x;
  const int arow = t >> 4, acg = t & 15;
  const int bng = t & 15;
  const int kbeg = ks * 256;
  float4 ra[4], rb0[2], rb1[2];
  auto LOAD = [&](int k0) {
    #pragma unroll
    for (int i = 0; i < 4; ++i)
      ra[i] = *reinterpret_cast<const float4*>(X + (size_t)(m0 + arow + 16 * i) * 1024 + k0 + acg * 4);
    #pragma unroll
    for (int i = 0; i < 2; ++i) {
      int k = 2 * ((t >> 4) + 16 * i);
      rb0[i] = *reinterpret_cast<const float4*>(Bp + (size_t)(k0 + k) * ldb + bc0 + bng * 4);
      rb1[i] = *reinterpret_cast<const float4*>(Bp + (size_t)(k0 + k + 1) * ldb + bc0 + bng * 4);
    }
  };
  LOAD(kbeg);
  const int wid = t >> 6, wr = wid >> 1, wc = wid & 1, lane = t & 63;
  const int lr = lane & 15, lk = lane >> 4;
  const int sw = (lr & 7) << 4;
  floatx4 acc[2][2];
  #pragma unroll
  for (int mt = 0; mt < 2; ++mt)
    #pragma unroll
    for (int nt = 0; nt < 2; ++nt)
      acc[mt][nt] = (floatx4){0.f, 0.f, 0.f, 0.f};
  for (int kt = 0; kt < 4; ++kt) {
    #pragma unroll
    for (int i = 0; i < 4; ++i) {
      int row = arow + 16 * i;
      ushort4 w;
      w.x = f2bf(ra[i].x); w.y = f2bf(ra[i].y); w.z = f2bf(ra[i].z); w.w = f2bf(ra[i].w);
      *reinterpret_cast<ushort4*>(Asc + row * 128 + ((acg * 8) ^ ((row & 7) << 4))) = w;
    }
    #pragma unroll
    for (int i = 0; i < 2; ++i) {
      int k = 2 * ((t >> 4) + 16 * i);
      const float* p0 = (const float*)&rb0[i];
      const float* p1 = (const float*)&rb1[i];
      #pragma unroll
      for (int j = 0; j < 4; ++j) {
        int n = bng * 4 + j;
        uint32_t v = (uint32_t)f2bf(p0[j]) | ((uint32_t)f2bf(p1[j]) << 16);
        *reinterpret_cast<uint32_t*>(Bsc + n * 128 + ((k * 2) ^ ((n & 7) << 4))) = v;
      }
    }
    __syncthreads();
    if (kt + 1 < 4) LOAD(kbeg + 64 * (kt + 1));
    #pragma unroll
    for (int kc = 0; kc < 2; ++kc) {
      short8 af[2], bf[2];
      #pragma unroll
      for (int mt = 0; mt < 2; ++mt)
        af[mt] = *reinterpret_cast<const short8*>(
            Asc + (wr * 32 + mt * 16 + lr) * 128 + ((kc * 64 + lk * 16) ^ sw));
      #pragma unroll
      for (int nt = 0; nt < 2; ++nt)
        bf[nt] = *reinterpret_cast<const short8*>(
            Bsc + (wc * 32 + nt * 16 + lr) * 128 + ((kc * 64 + lk * 16) ^ sw));
      #pragma unroll
      for (int mt = 0; mt < 2; ++mt)
        #pragma unroll
        for (int nt = 0; nt < 2; ++nt)
          acc[mt][nt] = __builtin_amdgcn_mfma_f32_16x16x32_bf16(af[mt], bf[nt], acc[mt][nt], 0, 0, 0);
    }
    __syncthreads();
  }
  float* Co = Cp + (size_t)ks * 524288;
  #pragma unroll
  for (int mt = 0; mt < 2; ++mt)
    #pragma unroll
    for (int nt = 0; nt < 2; ++nt)
      #pragma unroll
      for (int r = 0; r < 4; ++r) {
        int row = wr * 32 + mt * 16 + lk * 4 + r;
        int col = wc * 32 + nt * 16 + lr;
        Co[(size_t)(m0 + row) * 2048 + n0 + col] = acc[mt][nt][r];
      }
}

// ---------------------------------------------------------------------------
// Reduce the 4 QKV partials + RoPE on q/k heads. grid = 1280, block = 256.
// ---------------------------------------------------------------------------
__global__ __launch_bounds__(256) void rope_reduce_kernel(
    const float* __restrict__ Cp, float* __restrict__ QKV,
    const float* __restrict__ cs, const float* __restrict__ sn) {
  int idx = blockIdx.x * 256 + threadIdx.x;
  const float* P0 = Cp;
  const float* P1 = Cp + 524288;
  const float* P2p = Cp + 1048576;
  const float* P3 = Cp + 1572864;
  if (idx < 196608) {                 // 256 s * 24 heads * 32 pairs
    int dp = idx & 31;
    int head = (idx >> 5) % 24;       // 0..15 q heads, 16..23 k heads
    int s = idx / 768;
    int base = s * 2048 + head * 64;
    int a1 = base + dp, a2 = base + dp + 32;
    float x1 = P0[a1] + P1[a1] + P2p[a1] + P3[a1];
    float x2 = P0[a2] + P1[a2] + P2p[a2] + P3[a2];
    float c1 = cs[s * 64 + dp],      s1v = sn[s * 64 + dp];
    float c2 = cs[s * 64 + dp + 32], s2v = sn[s * 64 + dp + 32];
    QKV[a1] = x1 * c1 - x2 * s1v;   // q' = q*cos + rot_half(q)*sin
    QKV[a2] = x2 * c2 + x1 * s2v;
  } else {
    int i2 = idx - 196608;            // 131072 v elements
    int s = i2 >> 9, c = 1536 + (i2 & 511);
    int a = s * 2048 + c;
    QKV[a] = P0[a] + P1[a] + P2p[a] + P3[a];
  }
}

// ---------------------------------------------------------------------------
// FUSED QK^T + softmax + p_diff + PV. Block (g,u) computes its 16 needed
// aw-rows (h in {2g,2g+1} x rows {4u..4u+3} + mirrors) via in-block MFMA
// (4/wave) against the staged k, then runs the R15 t-loop. No awf global
// buffer. LDS: ksh 32K (swizzled, dual-use MFMA+scalar) + vsh 32K + qsh 2K
// + awsh bf16 8.25K = 74.5KB -> 2 blocks/CU (16 waves).
// grid = 256 (8 g * 32 u), block = 512.
// ---------------------------------------------------------------------------
__global__ __launch_bounds__(512) void pdiff_fused_kernel(
    const float* __restrict__ QKV, float* __restrict__ pOut,
    float* __restrict__ qkpart, float* __restrict__ vpart,
    float* __restrict__ attn_out) {
  __shared__ ushort ksh[16384];       // 32KB swizzled [t][d] bf16
  __shared__ ushort vsh[16384];       // 32KB linear  [t][d] bf16
  __shared__ ushort qsh[1024];        // 2KB  swizzled [a][d] bf16 (16 rows)
  __shared__ ushort awsh[16][264];    // 8.25KB bf16 (scale^2*log2e*qk)
  char* kshc = (char*)ksh;
  char* qshc = (char*)qsh;
  const int g = blockIdx.x >> 5;
  const int u = blockIdx.x & 31;
  const int t = threadIdx.x;
  // stage k (swizzled bf16) + v (linear bf16)
  #pragma unroll
  for (int i = 0; i < 8; ++i) {
    int fi = t + i * 512;              // 4096 float4 slots
    int tt = fi >> 4, c = (fi & 15) * 4;
    float4 kv = *reinterpret_cast<const float4*>(QKV + (size_t)tt * 2048 + 1024 + g * 64 + c);
    float4 vv = *reinterpret_cast<const float4*>(QKV + (size_t)tt * 2048 + 1536 + g * 64 + c);
    ushort4 wk, wv;
    wk.x = f2bf(kv.x); wk.y = f2bf(kv.y); wk.z = f2bf(kv.z); wk.w = f2bf(kv.w);
    wv.x = f2bf(vv.x); wv.y = f2bf(vv.y); wv.z = f2bf(vv.z); wv.w = f2bf(vv.w);
    *reinterpret_cast<ushort4*>(kshc + tt * 128 + ((c * 2) ^ ((tt & 7) << 4))) = wk;
    *reinterpret_cast<ushort4*>(&vsh[tt * 64 + c]) = wv;
  }
  { // stage the 16 q rows: a = pr*8 + mr*4 + jo
    int a = t >> 5;                    // 0..15
    int c = (t & 31) * 2;              // 0..62
    int pr = a >> 3, mr = (a >> 2) & 1, jo = a & 3;
    int s = mr ? 255 - (4 * u + jo) : 4 * u + jo;
    int hh = 2 * g + pr;
    float2 qv = *reinterpret_cast<const float2*>(QKV + (size_t)s * 2048 + hh * 64 + c);
    uint32_t pk = (uint32_t)f2bf(qv.x) | ((uint32_t)f2bf(qv.y) << 16);
    *reinterpret_cast<uint32_t*>(qshc + a * 128 + ((c * 2) ^ ((a & 7) << 4))) = pk;
  }
  __syncthreads();
  const int w = t >> 6, lane = t & 63;
  const int lr = lane & 15, lk = lane >> 4;
  const int sw = (lr & 7) << 4;
  const float AWS = SCALE * SCALE * LOG2E;
  // QK^T: 16 col-tiles, 2 per wave, 2 kc each
  #pragma unroll
  for (int q2 = 0; q2 < 2; ++q2) {
    int nt = 2 * w + q2;
    floatx4 acc = (floatx4){0.f, 0.f, 0.f, 0.f};
    #pragma unroll
    for (int kc = 0; kc < 2; ++kc) {
      short8 af = *reinterpret_cast<const short8*>(
          qshc + lr * 128 + ((kc * 64 + lk * 16) ^ sw));
      int tt = nt * 16 + lr;
      short8 bf = *reinterpret_cast<const short8*>(
          kshc + tt * 128 + ((kc * 64 + lk * 16) ^ ((tt & 7) << 4)));
      acc = __builtin_amdgcn_mfma_f32_16x16x32_bf16(af, bf, acc, 0, 0, 0);
    }
    #pragma unroll
    for (int r = 0; r < 4; ++r)
      awsh[lk * 4 + r][nt * 16 + lr] = f2bf(acc[r] * AWS);
  }
  __syncthreads();
  // t-loop (R15 math): e = 2^(aw - cd2*k), ep = 2^(8*aw); p = ep/Sp
  const int pr = w & 1, jo = w >> 1;
  const int h = 2 * g + pr;
  const int jj = 4 * u + jo;
  float qk_acc = 0.f, v_acc = 0.f;
  for (int r = 0; r < 2; ++r) {
    int a = pr * 8 + r * 4 + jo;
    int s = r ? 255 - jj : jj;
    size_t rowbase = ((size_t)h * 256 + s) * 256;
    float cd2 = (SCALE * LOG2E) * QKV[(size_t)s * 2048 + h * 64 + lane];
    float S1 = 0.f, S2 = 0.f, S3p = 0.f, Sp = 0.f, P2p = 0.f, AVp = 0.f;
    for (int tt = 0; tt <= s; ++tt) {
      float kf = bf2f(*reinterpret_cast<const ushort*>(
          kshc + tt * 128 + ((lane * 2) ^ ((tt & 7) << 4))));
      float vf = bf2f(vsh[tt * 64 + lane]);
      float aw = bf2f(awsh[a][tt]);
      float e  = exp2f(fmaf(-cd2, kf, aw));
      float ep = exp2f(aw * 8.0f);
      S1 += e;
      S2  = fmaf(e, e, S2);
      S3p = fmaf(e, ep, S3p);
      Sp += ep;
      P2p = fmaf(ep, ep, P2p);
      AVp = fmaf(ep, vf, AVp);
    }
    float invS1 = 1.f / S1;
    float invSp = 1.f / Sp;
    qk_acc += S2 * invS1 * invS1 - 2.f * S3p * invS1 * invSp + P2p * invSp * invSp;
    float av = AVp * invSp;
    attn_out[(size_t)s * 1024 + h * 64 + lane] = av;
    v_acc += fabsf(av);
    #pragma unroll
    for (int i = 0; i < 4; ++i) {
      int tc = lane + i * 64;
      pOut[rowbase + tc] = (tc <= s) ? exp2f(bf2f(awsh[a][tc]) * 8.0f) * invSp : 0.f;
    }
  }
  qkpart[((size_t)h * 128 + jj) * 64 + lane] = qk_acc;
  vpart [((size_t)h * 128 + jj) * 64 + lane] = v_acc;
}

// ---------------------------------------------------------------------------
// GEMM 2 + tail in ONE dispatch. Blocks 0..255: 32x32-tile FULL-K bf16 MFMA,
// direct write to out. Blocks 256..263: qk/v/o importance reductions.
// grid = 264, block = 256.  (verified R15)
// ---------------------------------------------------------------------------
__global__ __launch_bounds__(256) void gemm_o_tail_kernel(
    const float* __restrict__ A, const float* __restrict__ W,
    const float* __restrict__ qkpart, const float* __restrict__ vpart,
    float* __restrict__ out, float* __restrict__ qkout,
    float* __restrict__ vout, float* __restrict__ oout) {
  __shared__ ushort As[2048];   // 32 rows x 64 k bf16, XOR swizzle
  __shared__ ushort Bs[2048];   // 32 n    x 64 k
  char* Asc = (char*)As;
  char* Bsc = (char*)Bs;
  const int b = blockIdx.x, t = threadIdx.x;
  if (b < 256) {
    const int tm = b >> 5, tn = b & 31;       // 8 m x 32 n tiles
    const int m0 = tm * 32, n0 = tn * 32;
    const int arow = t >> 3, aslot = t & 7;   // A: 32 rows x 16 slots
    const int kp = t >> 3, ng = t & 7;        // B: 32 kpairs x 8 ngroups
    float4 ra[2], rb0, rb1;
    auto LOAD = [&](int k0) {
      #pragma unroll
      for (int i = 0; i < 2; ++i)
        ra[i] = *reinterpret_cast<const float4*>(A + (size_t)(m0 + arow) * 1024 + k0 + (aslot + 8 * i) * 4);
      rb0 = *reinterpret_cast<const float4*>(W + (size_t)(k0 + 2 * kp) * 1024 + n0 + ng * 4);
      rb1 = *reinterpret_cast<const float4*>(W + (size_t)(k0 + 2 * kp + 1) * 1024 + n0 + ng * 4);
    };
    LOAD(0);
    const int wid = t >> 6, qm = wid >> 1, qn = wid & 1, lane = t & 63;
    const int lr = lane & 15, lk = lane >> 4;
    const int sw = (lr & 7) << 4;
    floatx4 acc = (floatx4){0.f, 0.f, 0.f, 0.f};
    for (int kt = 0; kt < 16; ++kt) {
      #pragma unroll
      for (int i = 0; i < 2; ++i) {
        int c = (aslot + 8 * i) * 4;
        ushort4 wv;
        wv.x = f2bf(ra[i].x); wv.y = f2bf(ra[i].y); wv.z = f2bf(ra[i].z); wv.w = f2bf(ra[i].w);
        *reinterpret_cast<ushort4*>(Asc + arow * 128 + ((c * 2) ^ ((arow & 7) << 4))) = wv;
      }
      {
        const float* p0 = (const float*)&rb0;
        const float* p1 = (const float*)&rb1;
        #pragma unroll
        for (int j = 0; j < 4; ++j) {
          int n = ng * 4 + j;
          uint32_t v = (uint32_t)f2bf(p0[j]) | ((uint32_t)f2bf(p1[j]) << 16);
          *reinterpret_cast<uint32_t*>(Bsc + n * 128 + ((kp * 4) ^ ((n & 7) << 4))) = v;
        }
      }
      __syncthreads();
      if (kt + 1 < 16) LOAD(64 * (kt + 1));
      #pragma unroll
      for (int kc = 0; kc < 2; ++kc) {
        short8 af = *reinterpret_cast<const short8*>(
            Asc + (qm * 16 + lr) * 128 + ((kc * 64 + lk * 16) ^ sw));
        short8 bf = *reinterpret_cast<const short8*>(
            Bsc + (qn * 16 + lr) * 128 + ((kc * 64 + lk * 16) ^ sw));
        acc = __builtin_amdgcn_mfma_f32_16x16x32_bf16(af, bf, acc, 0, 0, 0);
      }
      __syncthreads();
    }
    #pragma unroll
    for (int r = 0; r < 4; ++r) {
      int row = m0 + qm * 16 + lk * 4 + r;
      int col = n0 + qn * 16 + lr;
      out[(size_t)row * 1024 + col] = acc[r];
    }
  } else {
    int idx = (b - 256) * 256 + t;            // 0..2047
    if (idx < 1024) {
      int h = idx >> 6, d = idx & 63;
      float sum = 0.f;
      for (int j = 0; j < 128; ++j) sum += qkpart[((size_t)h * 128 + j) * 64 + d];
      qkout[idx] = sum;
    } else {
      int c = idx - 1024;
      int h = c >> 6, d = c & 63;
      float sum = 0.f;
      for (int j = 0; j < 128; ++j) sum += vpart[((size_t)h * 128 + j) * 64 + d];
      vout[c] = sum;
      oout[c] = sum;
    }
  }
}

// ---------------------------------------------------------------------------
extern "C" void kernel_launch(void* const* d_in, const int* in_sizes, int n_in,
                              void* d_out, int out_size, void* d_ws, size_t ws_size,
                              hipStream_t stream) {
  const float* X    = (const float*)d_in[0];   // hidden_states (1,256,1024)
  const float* cosp = (const float*)d_in[1];   // (1,256,64)
  const float* sinp = (const float*)d_in[2];   // (1,256,64)
  // d_in[3] attention_mask: causal, implemented analytically
  const float* Wq   = (const float*)d_in[4];   // (1024,1024)
  const float* Wk   = (const float*)d_in[5];   // (1024,512)
  const float* Wv   = (const float*)d_in[6];   // (1024,512)
  const float* Wo   = (const float*)d_in[7];   // (1024,1024)

  float* out  = (float*)d_out;                 // 262144
  float* pOut = out + 262144;                  // 1048576
  float* qki  = pOut + 1048576;                // 1024
  float* vi   = qki + 1024;                    // 1024
  float* oi   = vi + 1024;                     // 1024

  float* ws       = (float*)d_ws;
  float* QKV      = ws;                        // 524288 (s-major, 2048 cols: q|k|v)
  float* attn_out = ws + 524288;               // 262144
  float* qkpart   = ws + 786432;               // 131072
  float* vpart    = ws + 917504;               // 131072
  float* scratch  = ws + 1048576;              // 2097152 (QKV partials x4)

  hipLaunchKernelGGL(gemm_qkv_kernel, dim3(512), dim3(256), 0, stream, X, Wq, Wk, Wv, scratch);
  hipLaunchKernelGGL(rope_reduce_kernel, dim3(1280), dim3(256), 0, stream, scratch, QKV, cosp, sinp);
  hipLaunchKernelGGL(pdiff_fused_kernel, dim3(256), dim3(512), 0, stream, QKV, pOut, qkpart, vpart, attn_out);
  hipLaunchKernelGGL(gemm_o_tail_kernel, dim3(264), dim3(256), 0, stream, attn_out, Wo, qkpart, vpart, out, qki, vi, oi);
}

// Round 19
// 53.398 us; speedup vs baseline: 1.2084x; 1.0497x over previous
//
#include <hip/hip_runtime.h>
#include <math.h>

// Problem constants: B=1, S=256, HID=1024, H=16, KV=8, D=64, N_REP=2
#define SCALE 0.125f   // 1/sqrt(64)
#define LOG2E 1.44269504088896340736f

typedef short short8 __attribute__((ext_vector_type(8)));
typedef float floatx4 __attribute__((ext_vector_type(4)));

static __device__ __forceinline__ ushort f2bf(float x) {
  uint32_t b = __float_as_uint(x);
  uint32_t r = (b + 0x7FFFu + ((b >> 16) & 1u)) >> 16;   // RNE
  return (ushort)r;
}
static __device__ __forceinline__ float bf2f(ushort u) {
  return __uint_as_float(((uint32_t)u) << 16);
}

// ---------------------------------------------------------------------------
// MFMA bf16 GEMM 1: X(256x1024) @ [Wq|Wk|Wv](1024x2048) -> QKV partials.
// K-split 4. grid = 512 (4 ksplit * 128 tiles), block = 256. (verified R8/R13)
// ---------------------------------------------------------------------------
__global__ __launch_bounds__(256) void gemm_qkv_kernel(
    const float* __restrict__ X, const float* __restrict__ Wq,
    const float* __restrict__ Wk, const float* __restrict__ Wv,
    float* __restrict__ Cp) {
  __shared__ ushort As[4096];
  __shared__ ushort Bs[4096];
  char* Asc = (char*)As;
  char* Bsc = (char*)Bs;
  const int bx = blockIdx.x;
  const int ks = bx >> 7;            // 0..3
  const int tile = bx & 127;         // 4 m-tiles x 32 n-tiles
  const int tile_n = tile & 31, tile_m = tile >> 5;
  const int n0 = tile_n * 64, m0 = tile_m * 64;
  const float* Bp; int ldb, bc0;
  if (n0 < 1024)      { Bp = Wq; ldb = 1024; bc0 = n0; }
  else if (n0 < 1536) { Bp = Wk; ldb = 512;  bc0 = n0 - 1024; }
  else                { Bp = Wv; ldb = 512;  bc0 = n0 - 1536; }
  const int t = threadIdx.x;
  const int arow = t >> 4, acg = t & 15;
  const int bng = t & 15;
  const int kbeg = ks * 256;
  float4 ra[4], rb0[2], rb1[2];
  auto LOAD = [&](int k0) {
    #pragma unroll
    for (int i = 0; i < 4; ++i)
      ra[i] = *reinterpret_cast<const float4*>(X + (size_t)(m0 + arow + 16 * i) * 1024 + k0 + acg * 4);
    #pragma unroll
    for (int i = 0; i < 2; ++i) {
      int k = 2 * ((t >> 4) + 16 * i);
      rb0[i] = *reinterpret_cast<const float4*>(Bp + (size_t)(k0 + k) * ldb + bc0 + bng * 4);
      rb1[i] = *reinterpret_cast<const float4*>(Bp + (size_t)(k0 + k + 1) * ldb + bc0 + bng * 4);
    }
  };
  LOAD(kbeg);
  const int wid = t >> 6, wr = wid >> 1, wc = wid & 1, lane = t & 63;
  const int lr = lane & 15, lk = lane >> 4;
  const int sw = (lr & 7) << 4;
  floatx4 acc[2][2];
  #pragma unroll
  for (int mt = 0; mt < 2; ++mt)
    #pragma unroll
    for (int nt = 0; nt < 2; ++nt)
      acc[mt][nt] = (floatx4){0.f, 0.f, 0.f, 0.f};
  for (int kt = 0; kt < 4; ++kt) {
    #pragma unroll
    for (int i = 0; i < 4; ++i) {
      int row = arow + 16 * i;
      ushort4 w;
      w.x = f2bf(ra[i].x); w.y = f2bf(ra[i].y); w.z = f2bf(ra[i].z); w.w = f2bf(ra[i].w);
      *reinterpret_cast<ushort4*>(Asc + row * 128 + ((acg * 8) ^ ((row & 7) << 4))) = w;
    }
    #pragma unroll
    for (int i = 0; i < 2; ++i) {
      int k = 2 * ((t >> 4) + 16 * i);
      const float* p0 = (const float*)&rb0[i];
      const float* p1 = (const float*)&rb1[i];
      #pragma unroll
      for (int j = 0; j < 4; ++j) {
        int n = bng * 4 + j;
        uint32_t v = (uint32_t)f2bf(p0[j]) | ((uint32_t)f2bf(p1[j]) << 16);
        *reinterpret_cast<uint32_t*>(Bsc + n * 128 + ((k * 2) ^ ((n & 7) << 4))) = v;
      }
    }
    __syncthreads();
    if (kt + 1 < 4) LOAD(kbeg + 64 * (kt + 1));
    #pragma unroll
    for (int kc = 0; kc < 2; ++kc) {
      short8 af[2], bf[2];
      #pragma unroll
      for (int mt = 0; mt < 2; ++mt)
        af[mt] = *reinterpret_cast<const short8*>(
            Asc + (wr * 32 + mt * 16 + lr) * 128 + ((kc * 64 + lk * 16) ^ sw));
      #pragma unroll
      for (int nt = 0; nt < 2; ++nt)
        bf[nt] = *reinterpret_cast<const short8*>(
            Bsc + (wc * 32 + nt * 16 + lr) * 128 + ((kc * 64 + lk * 16) ^ sw));
      #pragma unroll
      for (int mt = 0; mt < 2; ++mt)
        #pragma unroll
        for (int nt = 0; nt < 2; ++nt)
          acc[mt][nt] = __builtin_amdgcn_mfma_f32_16x16x32_bf16(af[mt], bf[nt], acc[mt][nt], 0, 0, 0);
    }
    __syncthreads();
  }
  float* Co = Cp + (size_t)ks * 524288;
  #pragma unroll
  for (int mt = 0; mt < 2; ++mt)
    #pragma unroll
    for (int nt = 0; nt < 2; ++nt)
      #pragma unroll
      for (int r = 0; r < 4; ++r) {
        int row = wr * 32 + mt * 16 + lk * 4 + r;
        int col = wc * 32 + nt * 16 + lr;
        Co[(size_t)(m0 + row) * 2048 + n0 + col] = acc[mt][nt][r];
      }
}

// ---------------------------------------------------------------------------
// Reduce the 4 QKV partials + RoPE on q/k heads. grid = 1280, block = 256.
// ---------------------------------------------------------------------------
__global__ __launch_bounds__(256) void rope_reduce_kernel(
    const float* __restrict__ Cp, float* __restrict__ QKV,
    const float* __restrict__ cs, const float* __restrict__ sn) {
  int idx = blockIdx.x * 256 + threadIdx.x;
  const float* P0 = Cp;
  const float* P1 = Cp + 524288;
  const float* P2p = Cp + 1048576;
  const float* P3 = Cp + 1572864;
  if (idx < 196608) {                 // 256 s * 24 heads * 32 pairs
    int dp = idx & 31;
    int head = (idx >> 5) % 24;       // 0..15 q heads, 16..23 k heads
    int s = idx / 768;
    int base = s * 2048 + head * 64;
    int a1 = base + dp, a2 = base + dp + 32;
    float x1 = P0[a1] + P1[a1] + P2p[a1] + P3[a1];
    float x2 = P0[a2] + P1[a2] + P2p[a2] + P3[a2];
    float c1 = cs[s * 64 + dp],      s1v = sn[s * 64 + dp];
    float c2 = cs[s * 64 + dp + 32], s2v = sn[s * 64 + dp + 32];
    QKV[a1] = x1 * c1 - x2 * s1v;   // q' = q*cos + rot_half(q)*sin
    QKV[a2] = x2 * c2 + x1 * s2v;
  } else {
    int i2 = idx - 196608;            // 131072 v elements
    int s = i2 >> 9, c = 1536 + (i2 & 511);
    int a = s * 2048 + c;
    QKV[a] = P0[a] + P1[a] + P2p[a] + P3[a];
  }
}

// ---------------------------------------------------------------------------
// FUSED QK^T + softmax + p_diff + PV, v2: VECTORIZED t-loop.
// kvT[d][260] u32 (k|v bf16, transposed): ds_read_b128 = 4 iterations/lane,
// no per-iter address math. Causal mask folded into awsh (-1000 beyond diag
// => e=ep=0), loop to (s+4)&~3, unrolled. MFMA aw phase as R18 (verified).
// LDS: ksh 32K + kvT 65K + qsh 2K + awsh 8.25K = 106KB -> 1 block/CU;
// latency hidden by ILP (4-8 independent iters in flight).
// grid = 256 (8 g * 32 u), block = 512.
// ---------------------------------------------------------------------------
__global__ __launch_bounds__(512) void pdiff_fused_kernel(
    const float* __restrict__ QKV, float* __restrict__ pOut,
    float* __restrict__ qkpart, float* __restrict__ vpart,
    float* __restrict__ attn_out) {
  __shared__ ushort ksh[16384];       // 32KB swizzled [t][d] bf16 (MFMA B)
  __shared__ uint32_t kvT[64 * 260];  // 65KB transposed [d][t]: k lo | v hi
  __shared__ ushort qsh[1024];        // 2KB  swizzled [a][d] bf16 (16 rows)
  __shared__ ushort awsh[16][264];    // 8.25KB bf16 (scale^2*log2e*qk, masked)
  char* kshc = (char*)ksh;
  char* qshc = (char*)qsh;
  const int g = blockIdx.x >> 5;
  const int u = blockIdx.x & 31;
  const int t = threadIdx.x;
  // stage k (swizzled, for MFMA) + kvT (transposed packed, for t-loop)
  #pragma unroll
  for (int i = 0; i < 8; ++i) {
    int fi = t + i * 512;              // 4096 float4 slots
    int tt = fi >> 4, c = (fi & 15) * 4;
    float4 kv = *reinterpret_cast<const float4*>(QKV + (size_t)tt * 2048 + 1024 + g * 64 + c);
    float4 vv = *reinterpret_cast<const float4*>(QKV + (size_t)tt * 2048 + 1536 + g * 64 + c);
    ushort4 wk;
    wk.x = f2bf(kv.x); wk.y = f2bf(kv.y); wk.z = f2bf(kv.z); wk.w = f2bf(kv.w);
    *reinterpret_cast<ushort4*>(kshc + tt * 128 + ((c * 2) ^ ((tt & 7) << 4))) = wk;
    kvT[(c + 0) * 260 + tt] = (uint32_t)wk.x | ((uint32_t)f2bf(vv.x) << 16);
    kvT[(c + 1) * 260 + tt] = (uint32_t)wk.y | ((uint32_t)f2bf(vv.y) << 16);
    kvT[(c + 2) * 260 + tt] = (uint32_t)wk.z | ((uint32_t)f2bf(vv.z) << 16);
    kvT[(c + 3) * 260 + tt] = (uint32_t)wk.w | ((uint32_t)f2bf(vv.w) << 16);
  }
  { // stage the 16 q rows: a = pr*8 + mr*4 + jo
    int a = t >> 5;                    // 0..15
    int c = (t & 31) * 2;              // 0..62
    int pr = a >> 3, mr = (a >> 2) & 1, jo = a & 3;
    int s = mr ? 255 - (4 * u + jo) : 4 * u + jo;
    int hh = 2 * g + pr;
    float2 qv = *reinterpret_cast<const float2*>(QKV + (size_t)s * 2048 + hh * 64 + c);
    uint32_t pk = (uint32_t)f2bf(qv.x) | ((uint32_t)f2bf(qv.y) << 16);
    *reinterpret_cast<uint32_t*>(qshc + a * 128 + ((c * 2) ^ ((a & 7) << 4))) = pk;
  }
  __syncthreads();
  const int w = t >> 6, lane = t & 63;
  const int lr = lane & 15, lk = lane >> 4;
  const int sw = (lr & 7) << 4;
  const float AWS = SCALE * SCALE * LOG2E;
  // QK^T: 16 col-tiles, 2 per wave; write awsh with causal mask baked in
  #pragma unroll
  for (int q2 = 0; q2 < 2; ++q2) {
    int nt = 2 * w + q2;
    floatx4 acc = (floatx4){0.f, 0.f, 0.f, 0.f};
    #pragma unroll
    for (int kc = 0; kc < 2; ++kc) {
      short8 af = *reinterpret_cast<const short8*>(
          qshc + lr * 128 + ((kc * 64 + lk * 16) ^ sw));
      int tt = nt * 16 + lr;
      short8 bf = *reinterpret_cast<const short8*>(
          kshc + tt * 128 + ((kc * 64 + lk * 16) ^ ((tt & 7) << 4)));
      acc = __builtin_amdgcn_mfma_f32_16x16x32_bf16(af, bf, acc, 0, 0, 0);
    }
    #pragma unroll
    for (int r = 0; r < 4; ++r) {
      int a = lk * 4 + r;
      int pr = a >> 3, mr = (a >> 2) & 1, jo = a & 3;
      int sa = mr ? 255 - (4 * u + jo) : 4 * u + jo;
      int tc = nt * 16 + lr;
      awsh[a][tc] = f2bf((tc <= sa) ? acc[r] * AWS : -1000.0f);
    }
  }
  __syncthreads();
  // t-loop, vectorized: b128 kvT (4 iters) + ushort4 awsh broadcast
  const int pr = w & 1, jo = w >> 1;
  const int h = 2 * g + pr;
  const int jj = 4 * u + jo;
  float qk_acc = 0.f, v_acc = 0.f;
  for (int r = 0; r < 2; ++r) {
    int a = pr * 8 + r * 4 + jo;
    int s = r ? 255 - jj : jj;
    size_t rowbase = ((size_t)h * 256 + s) * 256;
    float cd2 = (SCALE * LOG2E) * QKV[(size_t)s * 2048 + h * 64 + lane];
    float S1 = 0.f, S2 = 0.f, S3p = 0.f, Sp = 0.f, P2p = 0.f, AVp = 0.f;
    const uint32_t* kvrow = &kvT[lane * 260];
    const ushort* awrow = awsh[a];
    const int nt4 = (s + 4) & ~3;      // s+1 rounded up to mult of 4
    #pragma unroll 2
    for (int tb = 0; tb < nt4; tb += 4) {
      uint4 kv4 = *reinterpret_cast<const uint4*>(&kvrow[tb]);
      ushort4 aw4 = *reinterpret_cast<const ushort4*>(&awrow[tb]);
      uint32_t kvj[4] = {kv4.x, kv4.y, kv4.z, kv4.w};
      ushort awj[4] = {aw4.x, aw4.y, aw4.z, aw4.w};
      #pragma unroll
      for (int j = 0; j < 4; ++j) {
        float kf = __uint_as_float(kvj[j] << 16);
        float vf = __uint_as_float(kvj[j] & 0xFFFF0000u);
        float aw = bf2f(awj[j]);
        float e  = exp2f(fmaf(-cd2, kf, aw));
        float ep = exp2f(aw * 8.0f);
        S1 += e;
        S2  = fmaf(e, e, S2);
        S3p = fmaf(e, ep, S3p);
        Sp += ep;
        P2p = fmaf(ep, ep, P2p);
        AVp = fmaf(ep, vf, AVp);
      }
    }
    float invS1 = 1.f / S1;
    float invSp = 1.f / Sp;
    qk_acc += S2 * invS1 * invS1 - 2.f * S3p * invS1 * invSp + P2p * invSp * invSp;
    float av = AVp * invSp;
    attn_out[(size_t)s * 1024 + h * 64 + lane] = av;
    v_acc += fabsf(av);
    #pragma unroll
    for (int i = 0; i < 4; ++i) {
      int tc = lane + i * 64;
      pOut[rowbase + tc] = exp2f(bf2f(awrow[tc]) * 8.0f) * invSp;   // masked -> 0
    }
  }
  qkpart[((size_t)h * 128 + jj) * 64 + lane] = qk_acc;
  vpart [((size_t)h * 128 + jj) * 64 + lane] = v_acc;
}

// ---------------------------------------------------------------------------
// GEMM 2 + tail in ONE dispatch. Blocks 0..255: 32x32-tile FULL-K bf16 MFMA,
// direct write to out. Blocks 256..263: qk/v/o importance reductions.
// grid = 264, block = 256.  (verified R15)
// ---------------------------------------------------------------------------
__global__ __launch_bounds__(256) void gemm_o_tail_kernel(
    const float* __restrict__ A, const float* __restrict__ W,
    const float* __restrict__ qkpart, const float* __restrict__ vpart,
    float* __restrict__ out, float* __restrict__ qkout,
    float* __restrict__ vout, float* __restrict__ oout) {
  __shared__ ushort As[2048];   // 32 rows x 64 k bf16, XOR swizzle
  __shared__ ushort Bs[2048];   // 32 n    x 64 k
  char* Asc = (char*)As;
  char* Bsc = (char*)Bs;
  const int b = blockIdx.x, t = threadIdx.x;
  if (b < 256) {
    const int tm = b >> 5, tn = b & 31;       // 8 m x 32 n tiles
    const int m0 = tm * 32, n0 = tn * 32;
    const int arow = t >> 3, aslot = t & 7;   // A: 32 rows x 16 slots
    const int kp = t >> 3, ng = t & 7;        // B: 32 kpairs x 8 ngroups
    float4 ra[2], rb0, rb1;
    auto LOAD = [&](int k0) {
      #pragma unroll
      for (int i = 0; i < 2; ++i)
        ra[i] = *reinterpret_cast<const float4*>(A + (size_t)(m0 + arow) * 1024 + k0 + (aslot + 8 * i) * 4);
      rb0 = *reinterpret_cast<const float4*>(W + (size_t)(k0 + 2 * kp) * 1024 + n0 + ng * 4);
      rb1 = *reinterpret_cast<const float4*>(W + (size_t)(k0 + 2 * kp + 1) * 1024 + n0 + ng * 4);
    };
    LOAD(0);
    const int wid = t >> 6, qm = wid >> 1, qn = wid & 1, lane = t & 63;
    const int lr = lane & 15, lk = lane >> 4;
    const int sw = (lr & 7) << 4;
    floatx4 acc = (floatx4){0.f, 0.f, 0.f, 0.f};
    for (int kt = 0; kt < 16; ++kt) {
      #pragma unroll
      for (int i = 0; i < 2; ++i) {
        int c = (aslot + 8 * i) * 4;
        ushort4 wv;
        wv.x = f2bf(ra[i].x); wv.y = f2bf(ra[i].y); wv.z = f2bf(ra[i].z); wv.w = f2bf(ra[i].w);
        *reinterpret_cast<ushort4*>(Asc + arow * 128 + ((c * 2) ^ ((arow & 7) << 4))) = wv;
      }
      {
        const float* p0 = (const float*)&rb0;
        const float* p1 = (const float*)&rb1;
        #pragma unroll
        for (int j = 0; j < 4; ++j) {
          int n = ng * 4 + j;
          uint32_t v = (uint32_t)f2bf(p0[j]) | ((uint32_t)f2bf(p1[j]) << 16);
          *reinterpret_cast<uint32_t*>(Bsc + n * 128 + ((kp * 4) ^ ((n & 7) << 4))) = v;
        }
      }
      __syncthreads();
      if (kt + 1 < 16) LOAD(64 * (kt + 1));
      #pragma unroll
      for (int kc = 0; kc < 2; ++kc) {
        short8 af = *reinterpret_cast<const short8*>(
            Asc + (qm * 16 + lr) * 128 + ((kc * 64 + lk * 16) ^ sw));
        short8 bf = *reinterpret_cast<const short8*>(
            Bsc + (qn * 16 + lr) * 128 + ((kc * 64 + lk * 16) ^ sw));
        acc = __builtin_amdgcn_mfma_f32_16x16x32_bf16(af, bf, acc, 0, 0, 0);
      }
      __syncthreads();
    }
    #pragma unroll
    for (int r = 0; r < 4; ++r) {
      int row = m0 + qm * 16 + lk * 4 + r;
      int col = n0 + qn * 16 + lr;
      out[(size_t)row * 1024 + col] = acc[r];
    }
  } else {
    int idx = (b - 256) * 256 + t;            // 0..2047
    if (idx < 1024) {
      int h = idx >> 6, d = idx & 63;
      float sum = 0.f;
      for (int j = 0; j < 128; ++j) sum += qkpart[((size_t)h * 128 + j) * 64 + d];
      qkout[idx] = sum;
    } else {
      int c = idx - 1024;
      int h = c >> 6, d = c & 63;
      float sum = 0.f;
      for (int j = 0; j < 128; ++j) sum += vpart[((size_t)h * 128 + j) * 64 + d];
      vout[c] = sum;
      oout[c] = sum;
    }
  }
}

// ---------------------------------------------------------------------------
extern "C" void kernel_launch(void* const* d_in, const int* in_sizes, int n_in,
                              void* d_out, int out_size, void* d_ws, size_t ws_size,
                              hipStream_t stream) {
  const float* X    = (const float*)d_in[0];   // hidden_states (1,256,1024)
  const float* cosp = (const float*)d_in[1];   // (1,256,64)
  const float* sinp = (const float*)d_in[2];   // (1,256,64)
  // d_in[3] attention_mask: causal, implemented analytically
  const float* Wq   = (const float*)d_in[4];   // (1024,1024)
  const float* Wk   = (const float*)d_in[5];   // (1024,512)
  const float* Wv   = (const float*)d_in[6];   // (1024,512)
  const float* Wo   = (const float*)d_in[7];   // (1024,1024)

  float* out  = (float*)d_out;                 // 262144
  float* pOut = out + 262144;                  // 1048576
  float* qki  = pOut + 1048576;                // 1024
  float* vi   = qki + 1024;                    // 1024
  float* oi   = vi + 1024;                     // 1024

  float* ws       = (float*)d_ws;
  float* QKV      = ws;                        // 524288 (s-major, 2048 cols: q|k|v)
  float* attn_out = ws + 524288;               // 262144
  float* qkpart   = ws + 786432;               // 131072
  float* vpart    = ws + 917504;               // 131072
  float* scratch  = ws + 1048576;              // 2097152 (QKV partials x4)

  hipLaunchKernelGGL(gemm_qkv_kernel, dim3(512), dim3(256), 0, stream, X, Wq, Wk, Wv, scratch);
  hipLaunchKernelGGL(rope_reduce_kernel, dim3(1280), dim3(256), 0, stream, scratch, QKV, cosp, sinp);
  hipLaunchKernelGGL(pdiff_fused_kernel, dim3(256), dim3(512), 0, stream, QKV, pOut, qkpart, vpart, attn_out);
  hipLaunchKernelGGL(gemm_o_tail_kernel, dim3(264), dim3(256), 0, stream, attn_out, Wo, qkpart, vpart, out, qki, vi, oi);
}

// Round 20
// 43.119 us; speedup vs baseline: 1.4964x; 1.2384x over previous
//
#include <hip/hip_runtime.h>
#include <math.h>

// Problem constants: B=1, S=256, HID=1024, H=16, KV=8, D=64, N_REP=2
#define SCALE 0.125f   // 1/sqrt(64)
#define LOG2E 1.44269504088896340736f

typedef short short8 __attribute__((ext_vector_type(8)));
typedef float floatx4 __attribute__((ext_vector_type(4)));

static __device__ __forceinline__ ushort f2bf(float x) {
  uint32_t b = __float_as_uint(x);
  uint32_t r = (b + 0x7FFFu + ((b >> 16) & 1u)) >> 16;   // RNE
  return (ushort)r;
}
static __device__ __forceinline__ float bf2f(ushort u) {
  return __uint_as_float(((uint32_t)u) << 16);
}

// ---------------------------------------------------------------------------
// MFMA bf16 GEMM 1: X(256x1024) @ [Wq|Wk|Wv](1024x2048) -> QKV partials.
// K-split 4. grid = 512 (4 ksplit * 128 tiles), block = 256. (verified R8/R13)
// ---------------------------------------------------------------------------
__global__ __launch_bounds__(256) void gemm_qkv_kernel(
    const float* __restrict__ X, const float* __restrict__ Wq,
    const float* __restrict__ Wk, const float* __restrict__ Wv,
    float* __restrict__ Cp) {
  __shared__ ushort As[4096];
  __shared__ ushort Bs[4096];
  char* Asc = (char*)As;
  char* Bsc = (char*)Bs;
  const int bx = blockIdx.x;
  const int ks = bx >> 7;            // 0..3
  const int tile = bx & 127;         // 4 m-tiles x 32 n-tiles
  const int tile_n = tile & 31, tile_m = tile >> 5;
  const int n0 = tile_n * 64, m0 = tile_m * 64;
  const float* Bp; int ldb, bc0;
  if (n0 < 1024)      { Bp = Wq; ldb = 1024; bc0 = n0; }
  else if (n0 < 1536) { Bp = Wk; ldb = 512;  bc0 = n0 - 1024; }
  else                { Bp = Wv; ldb = 512;  bc0 = n0 - 1536; }
  const int t = threadIdx.x;
  const int arow = t >> 4, acg = t & 15;
  const int bng = t & 15;
  const int kbeg = ks * 256;
  float4 ra[4], rb0[2], rb1[2];
  auto LOAD = [&](int k0) {
    #pragma unroll
    for (int i = 0; i < 4; ++i)
      ra[i] = *reinterpret_cast<const float4*>(X + (size_t)(m0 + arow + 16 * i) * 1024 + k0 + acg * 4);
    #pragma unroll
    for (int i = 0; i < 2; ++i) {
      int k = 2 * ((t >> 4) + 16 * i);
      rb0[i] = *reinterpret_cast<const float4*>(Bp + (size_t)(k0 + k) * ldb + bc0 + bng * 4);
      rb1[i] = *reinterpret_cast<const float4*>(Bp + (size_t)(k0 + k + 1) * ldb + bc0 + bng * 4);
    }
  };
  LOAD(kbeg);
  const int wid = t >> 6, wr = wid >> 1, wc = wid & 1, lane = t & 63;
  const int lr = lane & 15, lk = lane >> 4;
  const int sw = (lr & 7) << 4;
  floatx4 acc[2][2];
  #pragma unroll
  for (int mt = 0; mt < 2; ++mt)
    #pragma unroll
    for (int nt = 0; nt < 2; ++nt)
      acc[mt][nt] = (floatx4){0.f, 0.f, 0.f, 0.f};
  for (int kt = 0; kt < 4; ++kt) {
    #pragma unroll
    for (int i = 0; i < 4; ++i) {
      int row = arow + 16 * i;
      ushort4 w;
      w.x = f2bf(ra[i].x); w.y = f2bf(ra[i].y); w.z = f2bf(ra[i].z); w.w = f2bf(ra[i].w);
      *reinterpret_cast<ushort4*>(Asc + row * 128 + ((acg * 8) ^ ((row & 7) << 4))) = w;
    }
    #pragma unroll
    for (int i = 0; i < 2; ++i) {
      int k = 2 * ((t >> 4) + 16 * i);
      const float* p0 = (const float*)&rb0[i];
      const float* p1 = (const float*)&rb1[i];
      #pragma unroll
      for (int j = 0; j < 4; ++j) {
        int n = bng * 4 + j;
        uint32_t v = (uint32_t)f2bf(p0[j]) | ((uint32_t)f2bf(p1[j]) << 16);
        *reinterpret_cast<uint32_t*>(Bsc + n * 128 + ((k * 2) ^ ((n & 7) << 4))) = v;
      }
    }
    __syncthreads();
    if (kt + 1 < 4) LOAD(kbeg + 64 * (kt + 1));
    #pragma unroll
    for (int kc = 0; kc < 2; ++kc) {
      short8 af[2], bf[2];
      #pragma unroll
      for (int mt = 0; mt < 2; ++mt)
        af[mt] = *reinterpret_cast<const short8*>(
            Asc + (wr * 32 + mt * 16 + lr) * 128 + ((kc * 64 + lk * 16) ^ sw));
      #pragma unroll
      for (int nt = 0; nt < 2; ++nt)
        bf[nt] = *reinterpret_cast<const short8*>(
            Bsc + (wc * 32 + nt * 16 + lr) * 128 + ((kc * 64 + lk * 16) ^ sw));
      #pragma unroll
      for (int mt = 0; mt < 2; ++mt)
        #pragma unroll
        for (int nt = 0; nt < 2; ++nt)
          acc[mt][nt] = __builtin_amdgcn_mfma_f32_16x16x32_bf16(af[mt], bf[nt], acc[mt][nt], 0, 0, 0);
    }
    __syncthreads();
  }
  float* Co = Cp + (size_t)ks * 524288;
  #pragma unroll
  for (int mt = 0; mt < 2; ++mt)
    #pragma unroll
    for (int nt = 0; nt < 2; ++nt)
      #pragma unroll
      for (int r = 0; r < 4; ++r) {
        int row = wr * 32 + mt * 16 + lk * 4 + r;
        int col = wc * 32 + nt * 16 + lr;
        Co[(size_t)(m0 + row) * 2048 + n0 + col] = acc[mt][nt][r];
      }
}

// ---------------------------------------------------------------------------
// Reduce the 4 QKV partials + RoPE on q/k heads. grid = 1280, block = 256.
// ---------------------------------------------------------------------------
__global__ __launch_bounds__(256) void rope_reduce_kernel(
    const float* __restrict__ Cp, float* __restrict__ QKV,
    const float* __restrict__ cs, const float* __restrict__ sn) {
  int idx = blockIdx.x * 256 + threadIdx.x;
  const float* P0 = Cp;
  const float* P1 = Cp + 524288;
  const float* P2p = Cp + 1048576;
  const float* P3 = Cp + 1572864;
  if (idx < 196608) {                 // 256 s * 24 heads * 32 pairs
    int dp = idx & 31;
    int head = (idx >> 5) % 24;       // 0..15 q heads, 16..23 k heads
    int s = idx / 768;
    int base = s * 2048 + head * 64;
    int a1 = base + dp, a2 = base + dp + 32;
    float x1 = P0[a1] + P1[a1] + P2p[a1] + P3[a1];
    float x2 = P0[a2] + P1[a2] + P2p[a2] + P3[a2];
    float c1 = cs[s * 64 + dp],      s1v = sn[s * 64 + dp];
    float c2 = cs[s * 64 + dp + 32], s2v = sn[s * 64 + dp + 32];
    QKV[a1] = x1 * c1 - x2 * s1v;   // q' = q*cos + rot_half(q)*sin
    QKV[a2] = x2 * c2 + x1 * s2v;
  } else {
    int i2 = idx - 196608;            // 131072 v elements
    int s = i2 >> 9, c = 1536 + (i2 & 511);
    int a = s * 2048 + c;
    QKV[a] = P0[a] + P1[a] + P2p[a] + P3[a];
  }
}

// ---------------------------------------------------------------------------
// FUSED QK^T + softmax + p_diff + PV, v3:
//  - native v_exp_f32 via __builtin_amdgcn_exp2f (exp2f was an OCML multi-
//    inst sequence -> ~half the VALU work, R19 counter evidence)
//  - ep = 2^(8*aw) hoisted per-ROW into epsh fp32 (lane-invariant: was 64x
//    redundant per-lane exp2) — wave-local rows, no extra barrier
//  - kvT stride 258 + 2x ds_read_b64: bank = (2*lane+tb)%32 -> 2-way alias
//    (free, m136); R19's stride-260 b128 was 8-way (917K conflicts)
// LDS: ksh 32K + kvT 64.5K + qsh 2K + awsh 8.25K + epsh 16.25K = 123KB.
// grid = 256 (8 g * 32 u), block = 512.
// ---------------------------------------------------------------------------
__global__ __launch_bounds__(512) void pdiff_fused_kernel(
    const float* __restrict__ QKV, float* __restrict__ pOut,
    float* __restrict__ qkpart, float* __restrict__ vpart,
    float* __restrict__ attn_out) {
  __shared__ ushort ksh[16384];       // 32KB swizzled [t][d] bf16 (MFMA B)
  __shared__ uint32_t kvT[64 * 258];  // 64.5KB transposed [d][t]: k lo | v hi
  __shared__ ushort qsh[1024];        // 2KB  swizzled [a][d] bf16 (16 rows)
  __shared__ ushort awsh[16][264];    // 8.25KB bf16 (scale^2*log2e*qk, masked)
  __shared__ float  epsh[16][260];    // 16.25KB fp32 2^(8*aw) per row
  char* kshc = (char*)ksh;
  char* qshc = (char*)qsh;
  const int g = blockIdx.x >> 5;
  const int u = blockIdx.x & 31;
  const int t = threadIdx.x;
  // stage k (swizzled, for MFMA) + kvT (transposed packed, for t-loop)
  #pragma unroll
  for (int i = 0; i < 8; ++i) {
    int fi = t + i * 512;              // 4096 float4 slots
    int tt = fi >> 4, c = (fi & 15) * 4;
    float4 kv = *reinterpret_cast<const float4*>(QKV + (size_t)tt * 2048 + 1024 + g * 64 + c);
    float4 vv = *reinterpret_cast<const float4*>(QKV + (size_t)tt * 2048 + 1536 + g * 64 + c);
    ushort4 wk;
    wk.x = f2bf(kv.x); wk.y = f2bf(kv.y); wk.z = f2bf(kv.z); wk.w = f2bf(kv.w);
    *reinterpret_cast<ushort4*>(kshc + tt * 128 + ((c * 2) ^ ((tt & 7) << 4))) = wk;
    kvT[(c + 0) * 258 + tt] = (uint32_t)wk.x | ((uint32_t)f2bf(vv.x) << 16);
    kvT[(c + 1) * 258 + tt] = (uint32_t)wk.y | ((uint32_t)f2bf(vv.y) << 16);
    kvT[(c + 2) * 258 + tt] = (uint32_t)wk.z | ((uint32_t)f2bf(vv.z) << 16);
    kvT[(c + 3) * 258 + tt] = (uint32_t)wk.w | ((uint32_t)f2bf(vv.w) << 16);
  }
  { // stage the 16 q rows: a = pr*8 + mr*4 + jo
    int a = t >> 5;                    // 0..15
    int c = (t & 31) * 2;              // 0..62
    int pr = a >> 3, mr = (a >> 2) & 1, jo = a & 3;
    int s = mr ? 255 - (4 * u + jo) : 4 * u + jo;
    int hh = 2 * g + pr;
    float2 qv = *reinterpret_cast<const float2*>(QKV + (size_t)s * 2048 + hh * 64 + c);
    uint32_t pk = (uint32_t)f2bf(qv.x) | ((uint32_t)f2bf(qv.y) << 16);
    *reinterpret_cast<uint32_t*>(qshc + a * 128 + ((c * 2) ^ ((a & 7) << 4))) = pk;
  }
  __syncthreads();
  const int w = t >> 6, lane = t & 63;
  const int lr = lane & 15, lk = lane >> 4;
  const int sw = (lr & 7) << 4;
  const float AWS = SCALE * SCALE * LOG2E;
  // QK^T: 16 col-tiles, 2 per wave; write awsh with causal mask baked in
  #pragma unroll
  for (int q2 = 0; q2 < 2; ++q2) {
    int nt = 2 * w + q2;
    floatx4 acc = (floatx4){0.f, 0.f, 0.f, 0.f};
    #pragma unroll
    for (int kc = 0; kc < 2; ++kc) {
      short8 af = *reinterpret_cast<const short8*>(
          qshc + lr * 128 + ((kc * 64 + lk * 16) ^ sw));
      int tt = nt * 16 + lr;
      short8 bf = *reinterpret_cast<const short8*>(
          kshc + tt * 128 + ((kc * 64 + lk * 16) ^ ((tt & 7) << 4)));
      acc = __builtin_amdgcn_mfma_f32_16x16x32_bf16(af, bf, acc, 0, 0, 0);
    }
    #pragma unroll
    for (int r = 0; r < 4; ++r) {
      int a = lk * 4 + r;
      int pr = a >> 3, mr = (a >> 2) & 1, jo = a & 3;
      int sa = mr ? 255 - (4 * u + jo) : 4 * u + jo;
      int tc = nt * 16 + lr;
      awsh[a][tc] = f2bf((tc <= sa) ? acc[r] * AWS : -1000.0f);
    }
  }
  __syncthreads();
  const int pr = w & 1, jo = w >> 1;
  const int h = 2 * g + pr;
  const int jj = 4 * u + jo;
  // precompute ep = 2^(8*aw) fp32 for this wave's OWN two rows (no barrier:
  // each wave reads back only rows it wrote; wave-internal lgkmcnt orders it)
  #pragma unroll
  for (int r = 0; r < 2; ++r) {
    int a = pr * 8 + r * 4 + jo;
    #pragma unroll
    for (int i = 0; i < 4; ++i) {
      int tc = lane + i * 64;
      epsh[a][tc] = __builtin_amdgcn_exp2f(8.0f * bf2f(awsh[a][tc]));
    }
  }
  // t-loop: 2x b64 kv (2-way alias, free) + broadcast ep/aw; 1 native exp/iter
  float qk_acc = 0.f, v_acc = 0.f;
  for (int r = 0; r < 2; ++r) {
    int a = pr * 8 + r * 4 + jo;
    int s = r ? 255 - jj : jj;
    size_t rowbase = ((size_t)h * 256 + s) * 256;
    float cd2 = (SCALE * LOG2E) * QKV[(size_t)s * 2048 + h * 64 + lane];
    float S1 = 0.f, S2 = 0.f, S3p = 0.f, Sp = 0.f, P2p = 0.f, AVp = 0.f;
    const uint32_t* kvrow = &kvT[lane * 258];
    const ushort* awrow = awsh[a];
    const float* eprow = epsh[a];
    const int nt4 = (s + 4) & ~3;      // s+1 rounded up to mult of 4
    #pragma unroll 2
    for (int tb = 0; tb < nt4; tb += 4) {
      uint2 kvA = *reinterpret_cast<const uint2*>(&kvrow[tb]);
      uint2 kvB = *reinterpret_cast<const uint2*>(&kvrow[tb + 2]);
      float4 ep4 = *reinterpret_cast<const float4*>(&eprow[tb]);
      ushort4 aw4 = *reinterpret_cast<const ushort4*>(&awrow[tb]);
      uint32_t kvj[4] = {kvA.x, kvA.y, kvB.x, kvB.y};
      ushort awj[4] = {aw4.x, aw4.y, aw4.z, aw4.w};
      float epj[4] = {ep4.x, ep4.y, ep4.z, ep4.w};
      #pragma unroll
      for (int j = 0; j < 4; ++j) {
        float kf = __uint_as_float(kvj[j] << 16);
        float vf = __uint_as_float(kvj[j] & 0xFFFF0000u);
        float aw = bf2f(awj[j]);
        float e  = __builtin_amdgcn_exp2f(fmaf(-cd2, kf, aw));
        float ep = epj[j];
        S1 += e;
        S2  = fmaf(e, e, S2);
        S3p = fmaf(e, ep, S3p);
        Sp += ep;
        P2p = fmaf(ep, ep, P2p);
        AVp = fmaf(ep, vf, AVp);
      }
    }
    float invS1 = 1.f / S1;
    float invSp = 1.f / Sp;
    qk_acc += S2 * invS1 * invS1 - 2.f * S3p * invS1 * invSp + P2p * invSp * invSp;
    float av = AVp * invSp;
    attn_out[(size_t)s * 1024 + h * 64 + lane] = av;
    v_acc += fabsf(av);
    #pragma unroll
    for (int i = 0; i < 4; ++i) {
      int tc = lane + i * 64;
      pOut[rowbase + tc] = eprow[tc] * invSp;   // masked -> ep=0 -> p=0
    }
  }
  qkpart[((size_t)h * 128 + jj) * 64 + lane] = qk_acc;
  vpart [((size_t)h * 128 + jj) * 64 + lane] = v_acc;
}

// ---------------------------------------------------------------------------
// GEMM 2 + tail in ONE dispatch. Blocks 0..255: 32x32-tile FULL-K bf16 MFMA,
// direct write to out. Blocks 256..263: qk/v/o importance reductions.
// grid = 264, block = 256.  (verified R15)
// ---------------------------------------------------------------------------
__global__ __launch_bounds__(256) void gemm_o_tail_kernel(
    const float* __restrict__ A, const float* __restrict__ W,
    const float* __restrict__ qkpart, const float* __restrict__ vpart,
    float* __restrict__ out, float* __restrict__ qkout,
    float* __restrict__ vout, float* __restrict__ oout) {
  __shared__ ushort As[2048];   // 32 rows x 64 k bf16, XOR swizzle
  __shared__ ushort Bs[2048];   // 32 n    x 64 k
  char* Asc = (char*)As;
  char* Bsc = (char*)Bs;
  const int b = blockIdx.x, t = threadIdx.x;
  if (b < 256) {
    const int tm = b >> 5, tn = b & 31;       // 8 m x 32 n tiles
    const int m0 = tm * 32, n0 = tn * 32;
    const int arow = t >> 3, aslot = t & 7;   // A: 32 rows x 16 slots
    const int kp = t >> 3, ng = t & 7;        // B: 32 kpairs x 8 ngroups
    float4 ra[2], rb0, rb1;
    auto LOAD = [&](int k0) {
      #pragma unroll
      for (int i = 0; i < 2; ++i)
        ra[i] = *reinterpret_cast<const float4*>(A + (size_t)(m0 + arow) * 1024 + k0 + (aslot + 8 * i) * 4);
      rb0 = *reinterpret_cast<const float4*>(W + (size_t)(k0 + 2 * kp) * 1024 + n0 + ng * 4);
      rb1 = *reinterpret_cast<const float4*>(W + (size_t)(k0 + 2 * kp + 1) * 1024 + n0 + ng * 4);
    };
    LOAD(0);
    const int wid = t >> 6, qm = wid >> 1, qn = wid & 1, lane = t & 63;
    const int lr = lane & 15, lk = lane >> 4;
    const int sw = (lr & 7) << 4;
    floatx4 acc = (floatx4){0.f, 0.f, 0.f, 0.f};
    for (int kt = 0; kt < 16; ++kt) {
      #pragma unroll
      for (int i = 0; i < 2; ++i) {
        int c = (aslot + 8 * i) * 4;
        ushort4 wv;
        wv.x = f2bf(ra[i].x); wv.y = f2bf(ra[i].y); wv.z = f2bf(ra[i].z); wv.w = f2bf(ra[i].w);
        *reinterpret_cast<ushort4*>(Asc + arow * 128 + ((c * 2) ^ ((arow & 7) << 4))) = wv;
      }
      {
        const float* p0 = (const float*)&rb0;
        const float* p1 = (const float*)&rb1;
        #pragma unroll
        for (int j = 0; j < 4; ++j) {
          int n = ng * 4 + j;
          uint32_t v = (uint32_t)f2bf(p0[j]) | ((uint32_t)f2bf(p1[j]) << 16);
          *reinterpret_cast<uint32_t*>(Bsc + n * 128 + ((kp * 4) ^ ((n & 7) << 4))) = v;
        }
      }
      __syncthreads();
      if (kt + 1 < 16) LOAD(64 * (kt + 1));
      #pragma unroll
      for (int kc = 0; kc < 2; ++kc) {
        short8 af = *reinterpret_cast<const short8*>(
            Asc + (qm * 16 + lr) * 128 + ((kc * 64 + lk * 16) ^ sw));
        short8 bf = *reinterpret_cast<const short8*>(
            Bsc + (qn * 16 + lr) * 128 + ((kc * 64 + lk * 16) ^ sw));
        acc = __builtin_amdgcn_mfma_f32_16x16x32_bf16(af, bf, acc, 0, 0, 0);
      }
      __syncthreads();
    }
    #pragma unroll
    for (int r = 0; r < 4; ++r) {
      int row = m0 + qm * 16 + lk * 4 + r;
      int col = n0 + qn * 16 + lr;
      out[(size_t)row * 1024 + col] = acc[r];
    }
  } else {
    int idx = (b - 256) * 256 + t;            // 0..2047
    if (idx < 1024) {
      int h = idx >> 6, d = idx & 63;
      float sum = 0.f;
      for (int j = 0; j < 128; ++j) sum += qkpart[((size_t)h * 128 + j) * 64 + d];
      qkout[idx] = sum;
    } else {
      int c = idx - 1024;
      int h = c >> 6, d = c & 63;
      float sum = 0.f;
      for (int j = 0; j < 128; ++j) sum += vpart[((size_t)h * 128 + j) * 64 + d];
      vout[c] = sum;
      oout[c] = sum;
    }
  }
}

// ---------------------------------------------------------------------------
extern "C" void kernel_launch(void* const* d_in, const int* in_sizes, int n_in,
                              void* d_out, int out_size, void* d_ws, size_t ws_size,
                              hipStream_t stream) {
  const float* X    = (const float*)d_in[0];   // hidden_states (1,256,1024)
  const float* cosp = (const float*)d_in[1];   // (1,256,64)
  const float* sinp = (const float*)d_in[2];   // (1,256,64)
  // d_in[3] attention_mask: causal, implemented analytically
  const float* Wq   = (const float*)d_in[4];   // (1024,1024)
  const float* Wk   = (const float*)d_in[5];   // (1024,512)
  const float* Wv   = (const float*)d_in[6];   // (1024,512)
  const float* Wo   = (const float*)d_in[7];   // (1024,1024)

  float* out  = (float*)d_out;                 // 262144
  float* pOut = out + 262144;                  // 1048576
  float* qki  = pOut + 1048576;                // 1024
  float* vi   = qki + 1024;                    // 1024
  float* oi   = vi + 1024;                     // 1024

  float* ws       = (float*)d_ws;
  float* QKV      = ws;                        // 524288 (s-major, 2048 cols: q|k|v)
  float* attn_out = ws + 524288;               // 262144
  float* qkpart   = ws + 786432;               // 131072
  float* vpart    = ws + 917504;               // 131072
  float* scratch  = ws + 1048576;              // 2097152 (QKV partials x4)

  hipLaunchKernelGGL(gemm_qkv_kernel, dim3(512), dim3(256), 0, stream, X, Wq, Wk, Wv, scratch);
  hipLaunchKernelGGL(rope_reduce_kernel, dim3(1280), dim3(256), 0, stream, scratch, QKV, cosp, sinp);
  hipLaunchKernelGGL(pdiff_fused_kernel, dim3(256), dim3(512), 0, stream, QKV, pOut, qkpart, vpart, attn_out);
  hipLaunchKernelGGL(gemm_o_tail_kernel, dim3(264), dim3(256), 0, stream, attn_out, Wo, qkpart, vpart, out, qki, vi, oi);
}